// Round 3
// baseline (938.875 us; speedup 1.0000x reference)
//
#include <hip/hip_runtime.h>
#include <hip/hip_bf16.h>
#include <stdint.h>

#define NN 65536
#define NE 1048576
#define E2 (NE + NN)      // edges + self loops = 1,114,112 = 8704*128
#define HID 128
#define LP 136            // LDS row pitch in fp16 elements (272 B = 17*16, keeps 16B align)

typedef _Float16 h8v __attribute__((ext_vector_type(8)));
typedef __fp16 fp16x2 __attribute__((ext_vector_type(2)));
typedef __attribute__((ext_vector_type(4))) float f32x4;

// pack two fp32 -> packed fp16 (RTZ, v_cvt_pkrtz_f16_f32)
__device__ __forceinline__ uint32_t pkh(float a, float b){
    union { fp16x2 h; uint32_t u; } v;
    v.h = __builtin_amdgcn_cvt_pkrtz(a, b);
    return v.u;
}
// monotone float->uint encoding for unsigned atomicMax
__device__ __forceinline__ uint32_t encf(float x){
    union { float f; uint32_t u; } v; v.f = x;
    return (v.u & 0x80000000u) ? ~v.u : (v.u | 0x80000000u);
}
__device__ __forceinline__ float decf(uint32_t u){
    union { uint32_t u; float f; } v;
    v.u = (u & 0x80000000u) ? (u ^ 0x80000000u) : ~u;
    return v.f;
}

// ---- stage one 64-elem half-row into LDS ----
__device__ __forceinline__ void stage_copy(const _Float16* g, _Float16* l){
    const uint4* gs = (const uint4*)g; uint4* ls = (uint4*)l;
    #pragma unroll
    for (int j = 0; j < 8; j++) ls[j] = gs[j];
}
__device__ __forceinline__ void stage_cvt(const float* g, _Float16* l){
    const float4* gs = (const float4*)g; uint4* ls = (uint4*)l;
    #pragma unroll
    for (int j = 0; j < 8; j++){
        float4 f0 = gs[2*j], f1 = gs[2*j+1];
        uint4 o; o.x = pkh(f0.x, f0.y); o.y = pkh(f0.z, f0.w);
        o.z = pkh(f1.x, f1.y); o.w = pkh(f1.z, f1.w);
        ls[j] = o;
    }
}

// 128x128x128 fp16 GEMM tile from LDS (used by k_ab / k_gnn)
__device__ __forceinline__ void gemm_tile(const _Float16* Ts, const _Float16* Ws,
                                          f32x4 (&acc)[2][8], int wv, int lq, int quad){
    #pragma unroll
    for (int k0 = 0; k0 < 128; k0 += 32){
        h8v af[2], bfr[8];
        #pragma unroll
        for (int rt = 0; rt < 2; rt++)
            af[rt] = *(const h8v*)(Ts + (wv*32 + rt*16 + lq)*LP + k0 + quad*8);
        #pragma unroll
        for (int ct = 0; ct < 8; ct++)
            bfr[ct] = *(const h8v*)(Ws + (ct*16 + lq)*LP + k0 + quad*8);
        #pragma unroll
        for (int rt = 0; rt < 2; rt++)
            #pragma unroll
            for (int ct = 0; ct < 8; ct++)
                acc[rt][ct] = __builtin_amdgcn_mfma_f32_16x16x32_f16(
                                  af[rt], bfr[ct], acc[rt][ct], 0, 0, 0);
    }
}

// ---------------- prep kernels ----------------
struct WT { const float* s[10]; _Float16* d[10]; };
__global__ void k_wT_all(WT w){
    int m = blockIdx.x >> 6;                       // 10 matrices x 64 blocks
    int t = (blockIdx.x & 63) * 256 + threadIdx.x; // 16384 elems each
    int n = t >> 7, k = t & 127;
    w.d[m][n*128 + k] = (_Float16)w.s[m][k*128 + n];
}
__global__ void k_init_cnt(uint32_t* cnt){
    int i = blockIdx.x * 256 + threadIdx.x;
    cnt[i] = 1u;                                   // self-loop pre-counted
}
__global__ void k_hist(const int* __restrict__ ei, uint32_t* cnt){
    int e = blockIdx.x * 256 + threadIdx.x;
    if (e < NE) atomicAdd(&cnt[ei[NE + e]], 1u);
}
__global__ void k_scan1(const uint32_t* __restrict__ cnt, uint32_t* __restrict__ bsum){
    __shared__ uint32_t ps[256];
    int t = threadIdx.x;
    ps[t] = cnt[blockIdx.x*256 + t]; __syncthreads();
    for (int off = 128; off > 0; off >>= 1){
        if (t < off) ps[t] += ps[t + off];
        __syncthreads();
    }
    if (t == 0) bsum[blockIdx.x] = ps[0];
}
__global__ void k_scan2(const uint32_t* __restrict__ bsum, uint32_t* __restrict__ bofs){
    __shared__ uint32_t ps[256];
    int t = threadIdx.x;
    uint32_t v = bsum[t];
    ps[t] = v; __syncthreads();
    for (int off = 1; off < 256; off <<= 1){
        uint32_t u = (t >= off) ? ps[t - off] : 0u;
        __syncthreads();
        ps[t] += u;
        __syncthreads();
    }
    bofs[t] = ps[t] - v;                           // exclusive
}
__global__ void k_scan3(const uint32_t* __restrict__ cnt, const uint32_t* __restrict__ bofs,
                        uint32_t* __restrict__ cur){
    __shared__ uint32_t ps[256];
    int t = threadIdx.x, i = blockIdx.x*256 + t;
    uint32_t v = cnt[i];
    ps[t] = v; __syncthreads();
    for (int off = 1; off < 256; off <<= 1){
        uint32_t u = (t >= off) ? ps[t - off] : 0u;
        __syncthreads();
        ps[t] += u;
        __syncthreads();
    }
    cur[i] = bofs[blockIdx.x] + ps[t] - v;         // exclusive within + block base
}
__global__ void k_scatter(const int* __restrict__ ei, uint32_t* cur,
                          uint2* __restrict__ sedge){
    int e = blockIdx.x * 256 + threadIdx.x;
    if (e >= E2) return;
    uint32_t s, d;
    if (e < NE){ s = (uint32_t)ei[e]; d = (uint32_t)ei[NE + e]; }
    else { s = d = (uint32_t)(e - NE); }
    uint32_t p = atomicAdd(&cur[d], 1u);
    sedge[p] = make_uint2(s, d);
}
__global__ void k_init_agg(uint32_t* agg){
    int i = blockIdx.x * 256 + threadIdx.x;
    uint4 v = make_uint4(0x007FFFFFu, 0x007FFFFFu, 0x007FFFFFu, 0x007FFFFFu); // enc(-inf)
    ((uint4*)agg)[i] = v;
}

// ---------------- A/B precompute: B = pos@W1b ; A = x@W1a + B + b1 ----------------
__launch_bounds__(256, 2)
__global__ void k_ab(const float* __restrict__ xf, const _Float16* __restrict__ xh,
                     const float* __restrict__ pos,
                     const _Float16* __restrict__ w1aT, const _Float16* __restrict__ w1bT,
                     const float* __restrict__ lb1,
                     _Float16* __restrict__ Ah, _Float16* __restrict__ Bh){
    __shared__ _Float16 Ts[128*LP];
    __shared__ _Float16 Ws[128*LP];
    __shared__ float b1s[128];
    const int tid = threadIdx.x;
    const int node0 = blockIdx.x * 128;
    if (tid < 128) b1s[tid] = lb1[tid];
    const int row = tid >> 1, half = tid & 1;
    _Float16* lT = Ts + row*LP + half*64;
    _Float16* lW = Ws + row*LP + half*64;

    // phase 1: pos tile + W1b^T
    stage_cvt(pos + (size_t)(node0 + row)*HID + half*64, lT);
    stage_copy(w1bT + row*HID + half*64, lW);
    __syncthreads();

    const int wv = tid >> 6, lane = tid & 63, lq = lane & 15, quad = lane >> 4;
    f32x4 acc[2][8];
    #pragma unroll
    for (int a = 0; a < 2; a++)
        #pragma unroll
        for (int b = 0; b < 8; b++)
            acc[a][b] = (f32x4){0.f, 0.f, 0.f, 0.f};

    gemm_tile(Ts, Ws, acc, wv, lq, quad);
    __syncthreads();

    // save B = pos @ W1b  (C layout: col=lane&15, row=quad*4+reg)
    #pragma unroll
    for (int rt = 0; rt < 2; rt++)
        #pragma unroll
        for (int ct = 0; ct < 8; ct++)
            #pragma unroll
            for (int rg = 0; rg < 4; rg++){
                int r = node0 + wv*32 + rt*16 + quad*4 + rg;
                int c = ct*16 + lq;
                Bh[(size_t)r*HID + c] = (_Float16)acc[rt][ct][rg];
            }

    // phase 2: x tile + W1a^T, continue accumulation
    if (xh) stage_copy(xh + (size_t)(node0 + row)*HID + half*64, lT);
    else    stage_cvt (xf + (size_t)(node0 + row)*HID + half*64, lT);
    stage_copy(w1aT + row*HID + half*64, lW);
    __syncthreads();

    gemm_tile(Ts, Ws, acc, wv, lq, quad);

    #pragma unroll
    for (int rt = 0; rt < 2; rt++)
        #pragma unroll
        for (int ct = 0; ct < 8; ct++)
            #pragma unroll
            for (int rg = 0; rg < 4; rg++){
                int r = node0 + wv*32 + rt*16 + quad*4 + rg;
                int c = ct*16 + lq;
                Ah[(size_t)r*HID + c] = (_Float16)(acc[rt][ct][rg] + b1s[c]);
            }
}

// -------- edge kernel: h = relu(A[src]-B[dst]) @ W2 + b2 ; segmented max into agg --------
// No A-tile LDS: each MFMA lane gathers its own fragment. Epilogue in registers.
__launch_bounds__(256, 4)
__global__ void k_edge(const uint2* __restrict__ sedge,
                       const _Float16* __restrict__ Ah, const _Float16* __restrict__ Bh,
                       const _Float16* __restrict__ w2T, const float* __restrict__ lb2,
                       uint32_t* __restrict__ agg){
    __shared__ _Float16 Ws[128*LP];
    __shared__ int ss_s[128];
    __shared__ int ds_s[128];
    __shared__ float b2s[128];
    const int tid = threadIdx.x;
    const int e0 = blockIdx.x * 128;
    const int row = tid >> 1, half = tid & 1;

    if (tid < 128){
        uint2 e = sedge[e0 + tid];
        ss_s[tid] = (int)e.x; ds_s[tid] = (int)e.y;
        b2s[tid] = lb2[tid];
    }
    stage_copy(w2T + row*HID + half*64, Ws + row*LP + half*64);
    __syncthreads();

    const int wv = tid >> 6, lane = tid & 63, lq = lane & 15, quad = lane >> 4;
    const int r0 = wv*32 + lq, r1 = wv*32 + 16 + lq;
    const _Float16* a0p = Ah + (size_t)ss_s[r0]*HID + quad*8;
    const _Float16* a1p = Ah + (size_t)ss_s[r1]*HID + quad*8;
    const _Float16* b0p = Bh + (size_t)ds_s[r0]*HID + quad*8;
    const _Float16* b1p = Bh + (size_t)ds_s[r1]*HID + quad*8;

    f32x4 acc[2][8];
    #pragma unroll
    for (int a = 0; a < 2; a++)
        #pragma unroll
        for (int b = 0; b < 8; b++)
            acc[a][b] = (f32x4){0.f, 0.f, 0.f, 0.f};

    const h8v zero8 = (h8v)(_Float16)0;
    #pragma unroll
    for (int k0 = 0; k0 < 128; k0 += 32){
        h8v a0 = *(const h8v*)(a0p + k0) - *(const h8v*)(b0p + k0);
        h8v a1 = *(const h8v*)(a1p + k0) - *(const h8v*)(b1p + k0);
        a0 = __builtin_elementwise_max(a0, zero8);
        a1 = __builtin_elementwise_max(a1, zero8);
        #pragma unroll
        for (int ct = 0; ct < 8; ct++){
            h8v b = *(const h8v*)(Ws + (ct*16 + lq)*LP + k0 + quad*8);
            acc[0][ct] = __builtin_amdgcn_mfma_f32_16x16x32_f16(a0, b, acc[0][ct], 0, 0, 0);
            acc[1][ct] = __builtin_amdgcn_mfma_f32_16x16x32_f16(a1, b, acc[1][ct], 0, 0, 0);
        }
    }

    // register epilogue: rows quad*4+rg are 4 consecutive (dst-sorted) edges
    const float NEG = -__builtin_inff();
    #pragma unroll
    for (int rt = 0; rt < 2; rt++){
        const int rb = wv*32 + rt*16 + quad*4;
        const int d0 = ds_s[rb], d1 = ds_s[rb+1], d2 = ds_s[rb+2], d3 = ds_s[rb+3];
        #pragma unroll
        for (int ct = 0; ct < 8; ct++){
            const int c = ct*16 + lq;
            const float bias = b2s[c];
            float v0 = acc[rt][ct][0] + bias, v1 = acc[rt][ct][1] + bias;
            float v2 = acc[rt][ct][2] + bias, v3 = acc[rt][ct][3] + bias;
            float m = v0; int cd = d0;
            if (d1 != cd){ atomicMax(&agg[(size_t)cd*HID + c], encf(m)); m = NEG; cd = d1; }
            m = fmaxf(m, v1);
            if (d2 != cd){ atomicMax(&agg[(size_t)cd*HID + c], encf(m)); m = NEG; cd = d2; }
            m = fmaxf(m, v2);
            if (d3 != cd){ atomicMax(&agg[(size_t)cd*HID + c], encf(m)); m = NEG; cd = d3; }
            m = fmaxf(m, v3);
            atomicMax(&agg[(size_t)cd*HID + c], encf(m));
        }
    }
}

// -------- global nn: out = relu(agg@G1 + c1) @ G2 + c2 --------
__launch_bounds__(256, 2)
__global__ void k_gnn(const uint32_t* __restrict__ agg,
                      const _Float16* __restrict__ g1T, const _Float16* __restrict__ g2T,
                      const float* __restrict__ gb1, const float* __restrict__ gb2,
                      float* __restrict__ outf, _Float16* __restrict__ outh){
    __shared__ _Float16 Ts[128*LP];
    __shared__ _Float16 Ws[128*LP];
    __shared__ float c1s[128];
    __shared__ float c2s[128];
    const int tid = threadIdx.x;
    const int node0 = blockIdx.x * 128;
    if (tid < 128){ c1s[tid] = gb1[tid]; c2s[tid] = gb2[tid]; }
    const int row = tid >> 1, half = tid & 1;
    _Float16* lW = Ws + row*LP + half*64;

    {   // decode agg tile + stage G1^T
        const uint4* ga = (const uint4*)(agg + (size_t)(node0 + row)*HID + half*64);
        _Float16* lt = Ts + row*LP + half*64;
        #pragma unroll
        for (int j = 0; j < 16; j++){
            uint4 u = ga[j];
            uint2 o; o.x = pkh(decf(u.x), decf(u.y)); o.y = pkh(decf(u.z), decf(u.w));
            *(uint2*)(lt + j*4) = o;
        }
        stage_copy(g1T + row*HID + half*64, lW);
    }
    __syncthreads();

    const int wv = tid >> 6, lane = tid & 63, lq = lane & 15, quad = lane >> 4;
    f32x4 acc[2][8];
    #pragma unroll
    for (int a = 0; a < 2; a++)
        #pragma unroll
        for (int b = 0; b < 8; b++)
            acc[a][b] = (f32x4){0.f, 0.f, 0.f, 0.f};

    gemm_tile(Ts, Ws, acc, wv, lq, quad);
    __syncthreads();

    // P = relu(acc + c1) -> Ts ; restage Ws <- G2^T
    #pragma unroll
    for (int rt = 0; rt < 2; rt++)
        #pragma unroll
        for (int ct = 0; ct < 8; ct++)
            #pragma unroll
            for (int rg = 0; rg < 4; rg++){
                int rr = wv*32 + rt*16 + quad*4 + rg;
                int c  = ct*16 + lq;
                Ts[rr*LP + c] = (_Float16)fmaxf(acc[rt][ct][rg] + c1s[c], 0.f);
            }
    stage_copy(g2T + row*HID + half*64, lW);
    __syncthreads();

    #pragma unroll
    for (int a = 0; a < 2; a++)
        #pragma unroll
        for (int b = 0; b < 8; b++)
            acc[a][b] = (f32x4){0.f, 0.f, 0.f, 0.f};

    gemm_tile(Ts, Ws, acc, wv, lq, quad);

    #pragma unroll
    for (int rt = 0; rt < 2; rt++)
        #pragma unroll
        for (int ct = 0; ct < 8; ct++)
            #pragma unroll
            for (int rg = 0; rg < 4; rg++){
                int r = node0 + wv*32 + rt*16 + quad*4 + rg;
                int c = ct*16 + lq;
                float v = acc[rt][ct][rg] + c2s[c];
                if (outf) outf[(size_t)r*HID + c] = v;
                else      outh[(size_t)r*HID + c] = (_Float16)v;
            }
}

extern "C" void kernel_launch(void* const* d_in, const int* in_sizes, int n_in,
                              void* d_out, int out_size, void* d_ws, size_t ws_size,
                              hipStream_t stream){
    const float* x   = (const float*)d_in[0];
    const float* pos = (const float*)d_in[1];
    const int*   ei  = (const int*)d_in[2];
    const float* W[16];
    for (int i = 0; i < 16; i++) W[i] = (const float*)d_in[3 + i];
    // per layer l: lw1=W[8l+0] lb1=+1 lw2=+2 lb2=+3 gw1=+4 gb1=+5 gw2=+6 gb2=+7

    uint8_t* p = (uint8_t*)d_ws;
    _Float16* wT[10];
    for (int i = 0; i < 10; i++) wT[i] = (_Float16*)(p + (size_t)i * 32768);
    size_t off = 10 * 32768;
    _Float16* h0 = (_Float16*)(p + off); off += (size_t)NN * HID * 2;
    _Float16* Ah = (_Float16*)(p + off); off += (size_t)NN * HID * 2;
    _Float16* Bh = (_Float16*)(p + off); off += (size_t)NN * HID * 2;
    uint32_t* agg = (uint32_t*)(p + off); off += (size_t)NN * HID * 4;
    uint32_t* cnt = (uint32_t*)(p + off); off += (size_t)NN * 4;
    uint32_t* cur = (uint32_t*)(p + off); off += (size_t)NN * 4;
    uint32_t* bsum = (uint32_t*)(p + off); off += 256 * 4;
    uint32_t* bofs = (uint32_t*)(p + off); off += 256 * 4;
    uint2* sedge = (uint2*)(p + off); off += (size_t)E2 * 8;
    (void)ws_size; (void)in_sizes; (void)n_in; (void)out_size;

    // weight transpose+cvt: slots per layer: W1a^T, W1b^T, W2^T, G1^T, G2^T
    WT wt;
    for (int l = 0; l < 2; l++){
        wt.s[5*l + 0] = W[8*l + 0];
        wt.s[5*l + 1] = W[8*l + 0] + 128*128;
        wt.s[5*l + 2] = W[8*l + 2];
        wt.s[5*l + 3] = W[8*l + 4];
        wt.s[5*l + 4] = W[8*l + 6];
        for (int j = 0; j < 5; j++) wt.d[5*l + j] = wT[5*l + j];
    }
    k_wT_all<<<640, 256, 0, stream>>>(wt);

    // dst-sorted edge list (shared by both layers)
    k_init_cnt<<<NN/256, 256, 0, stream>>>(cnt);
    k_hist<<<NE/256, 256, 0, stream>>>(ei, cnt);
    k_scan1<<<256, 256, 0, stream>>>(cnt, bsum);
    k_scan2<<<1, 256, 0, stream>>>(bsum, bofs);
    k_scan3<<<256, 256, 0, stream>>>(cnt, bofs, cur);
    k_scatter<<<(E2 + 255)/256, 256, 0, stream>>>(ei, cur, sedge);

    for (int l = 0; l < 2; l++){
        const float* lb1 = W[8*l + 1], *lb2 = W[8*l + 3];
        const float* gb1 = W[8*l + 5], *gb2 = W[8*l + 7];
        k_ab<<<NN/128, 256, 0, stream>>>(l == 0 ? x : nullptr, l == 0 ? nullptr : h0,
                                         pos, wT[5*l + 0], wT[5*l + 1], lb1, Ah, Bh);
        k_init_agg<<<(NN*HID/4)/256, 256, 0, stream>>>(agg);
        k_edge<<<E2/128, 256, 0, stream>>>(sedge, Ah, Bh, wT[5*l + 2], lb2, agg);
        k_gnn<<<NN/128, 256, 0, stream>>>(agg, wT[5*l + 3], wT[5*l + 4], gb1, gb2,
                                          l == 0 ? nullptr : (float*)d_out,
                                          l == 0 ? h0 : nullptr);
    }
}

// Round 4
// 609.348 us; speedup vs baseline: 1.5408x; 1.5408x over previous
//
#include <hip/hip_runtime.h>
#include <hip/hip_bf16.h>
#include <stdint.h>

#define NN 65536
#define NE 1048576
#define E2 (NE + NN)      // edges + self loops = 1,114,112 = 8704*128
#define HID 128
#define LP 136            // LDS row pitch in fp16 elements (272 B = 17*16, keeps 16B align)

typedef _Float16 h8v __attribute__((ext_vector_type(8)));
typedef __fp16 fp16x2 __attribute__((ext_vector_type(2)));
typedef __attribute__((ext_vector_type(4))) float f32x4;

// pack two fp32 -> packed fp16 (RTZ, v_cvt_pkrtz_f16_f32)
__device__ __forceinline__ uint32_t pkh(float a, float b){
    union { fp16x2 h; uint32_t u; } v;
    v.h = __builtin_amdgcn_cvt_pkrtz(a, b);
    return v.u;
}
// monotone float->uint encoding for unsigned atomicMax
__device__ __forceinline__ uint32_t encf(float x){
    union { float f; uint32_t u; } v; v.f = x;
    return (v.u & 0x80000000u) ? ~v.u : (v.u | 0x80000000u);
}
__device__ __forceinline__ float decf(uint32_t u){
    union { uint32_t u; float f; } v;
    v.u = (u & 0x80000000u) ? (u ^ 0x80000000u) : ~u;
    return v.f;
}

// ---- stage one 64-elem half-row into LDS ----
__device__ __forceinline__ void stage_copy(const _Float16* g, _Float16* l){
    const uint4* gs = (const uint4*)g; uint4* ls = (uint4*)l;
    #pragma unroll
    for (int j = 0; j < 8; j++) ls[j] = gs[j];
}
__device__ __forceinline__ void stage_cvt(const float* g, _Float16* l){
    const float4* gs = (const float4*)g; uint4* ls = (uint4*)l;
    #pragma unroll
    for (int j = 0; j < 8; j++){
        float4 f0 = gs[2*j], f1 = gs[2*j+1];
        uint4 o; o.x = pkh(f0.x, f0.y); o.y = pkh(f0.z, f0.w);
        o.z = pkh(f1.x, f1.y); o.w = pkh(f1.z, f1.w);
        ls[j] = o;
    }
}

// 128x128x128 fp16 GEMM tile from LDS (used by k_ab / k_gnn)
__device__ __forceinline__ void gemm_tile(const _Float16* Ts, const _Float16* Ws,
                                          f32x4 (&acc)[2][8], int wv, int lq, int quad){
    #pragma unroll
    for (int k0 = 0; k0 < 128; k0 += 32){
        h8v af[2], bfr[8];
        #pragma unroll
        for (int rt = 0; rt < 2; rt++)
            af[rt] = *(const h8v*)(Ts + (wv*32 + rt*16 + lq)*LP + k0 + quad*8);
        #pragma unroll
        for (int ct = 0; ct < 8; ct++)
            bfr[ct] = *(const h8v*)(Ws + (ct*16 + lq)*LP + k0 + quad*8);
        #pragma unroll
        for (int rt = 0; rt < 2; rt++)
            #pragma unroll
            for (int ct = 0; ct < 8; ct++)
                acc[rt][ct] = __builtin_amdgcn_mfma_f32_16x16x32_f16(
                                  af[rt], bfr[ct], acc[rt][ct], 0, 0, 0);
    }
}

// ---------------- prep kernels ----------------
struct WT { const float* s[10]; _Float16* d[10]; };
__global__ void k_wT_all(WT w){
    int m = blockIdx.x >> 6;                       // 10 matrices x 64 blocks
    int t = (blockIdx.x & 63) * 256 + threadIdx.x; // 16384 elems each
    int n = t >> 7, k = t & 127;
    w.d[m][n*128 + k] = (_Float16)w.s[m][k*128 + n];
}
__global__ void k_init_cnt(uint32_t* cnt){
    int i = blockIdx.x * 256 + threadIdx.x;
    cnt[i] = 1u;                                   // self-loop pre-counted
}
__global__ void k_hist(const int* __restrict__ ei, uint32_t* cnt){
    int e = blockIdx.x * 256 + threadIdx.x;
    if (e < NE) atomicAdd(&cnt[ei[NE + e]], 1u);
}
__global__ void k_scan1(const uint32_t* __restrict__ cnt, uint32_t* __restrict__ bsum){
    __shared__ uint32_t ps[256];
    int t = threadIdx.x;
    ps[t] = cnt[blockIdx.x*256 + t]; __syncthreads();
    for (int off = 128; off > 0; off >>= 1){
        if (t < off) ps[t] += ps[t + off];
        __syncthreads();
    }
    if (t == 0) bsum[blockIdx.x] = ps[0];
}
__global__ void k_scan2(const uint32_t* __restrict__ bsum, uint32_t* __restrict__ bofs){
    __shared__ uint32_t ps[256];
    int t = threadIdx.x;
    uint32_t v = bsum[t];
    ps[t] = v; __syncthreads();
    for (int off = 1; off < 256; off <<= 1){
        uint32_t u = (t >= off) ? ps[t - off] : 0u;
        __syncthreads();
        ps[t] += u;
        __syncthreads();
    }
    bofs[t] = ps[t] - v;                           // exclusive
}
__global__ void k_scan3(const uint32_t* __restrict__ cnt, const uint32_t* __restrict__ bofs,
                        uint32_t* __restrict__ cur){
    __shared__ uint32_t ps[256];
    int t = threadIdx.x, i = blockIdx.x*256 + t;
    uint32_t v = cnt[i];
    ps[t] = v; __syncthreads();
    for (int off = 1; off < 256; off <<= 1){
        uint32_t u = (t >= off) ? ps[t - off] : 0u;
        __syncthreads();
        ps[t] += u;
        __syncthreads();
    }
    cur[i] = bofs[blockIdx.x] + ps[t] - v;         // exclusive within + block base
}
__global__ void k_scatter(const int* __restrict__ ei, uint32_t* cur,
                          uint2* __restrict__ sedge){
    int e = blockIdx.x * 256 + threadIdx.x;
    if (e >= E2) return;
    uint32_t s, d;
    if (e < NE){ s = (uint32_t)ei[e]; d = (uint32_t)ei[NE + e]; }
    else { s = d = (uint32_t)(e - NE); }
    uint32_t p = atomicAdd(&cur[d], 1u);
    sedge[p] = make_uint2(s, d);
}
__global__ void k_init_agg(uint32_t* agg){
    int i = blockIdx.x * 256 + threadIdx.x;
    uint4 v = make_uint4(0x007FFFFFu, 0x007FFFFFu, 0x007FFFFFu, 0x007FFFFFu); // enc(-inf)
    ((uint4*)agg)[i] = v;
}

// ---------------- A/B precompute: B = pos@W1b ; A = x@W1a + B + b1 ----------------
__launch_bounds__(256, 2)
__global__ void k_ab(const float* __restrict__ xf, const _Float16* __restrict__ xh,
                     const float* __restrict__ pos,
                     const _Float16* __restrict__ w1aT, const _Float16* __restrict__ w1bT,
                     const float* __restrict__ lb1,
                     _Float16* __restrict__ Ah, _Float16* __restrict__ Bh){
    __shared__ _Float16 Ts[128*LP];
    __shared__ _Float16 Ws[128*LP];
    __shared__ float b1s[128];
    const int tid = threadIdx.x;
    const int node0 = blockIdx.x * 128;
    if (tid < 128) b1s[tid] = lb1[tid];
    const int row = tid >> 1, half = tid & 1;
    _Float16* lT = Ts + row*LP + half*64;
    _Float16* lW = Ws + row*LP + half*64;

    // phase 1: pos tile + W1b^T
    stage_cvt(pos + (size_t)(node0 + row)*HID + half*64, lT);
    stage_copy(w1bT + row*HID + half*64, lW);
    __syncthreads();

    const int wv = tid >> 6, lane = tid & 63, lq = lane & 15, quad = lane >> 4;
    f32x4 acc[2][8];
    #pragma unroll
    for (int a = 0; a < 2; a++)
        #pragma unroll
        for (int b = 0; b < 8; b++)
            acc[a][b] = (f32x4){0.f, 0.f, 0.f, 0.f};

    gemm_tile(Ts, Ws, acc, wv, lq, quad);
    __syncthreads();

    // save B = pos @ W1b  (C layout: col=lane&15, row=quad*4+reg)
    #pragma unroll
    for (int rt = 0; rt < 2; rt++)
        #pragma unroll
        for (int ct = 0; ct < 8; ct++)
            #pragma unroll
            for (int rg = 0; rg < 4; rg++){
                int r = node0 + wv*32 + rt*16 + quad*4 + rg;
                int c = ct*16 + lq;
                Bh[(size_t)r*HID + c] = (_Float16)acc[rt][ct][rg];
            }

    // phase 2: x tile + W1a^T, continue accumulation
    if (xh) stage_copy(xh + (size_t)(node0 + row)*HID + half*64, lT);
    else    stage_cvt (xf + (size_t)(node0 + row)*HID + half*64, lT);
    stage_copy(w1aT + row*HID + half*64, lW);
    __syncthreads();

    gemm_tile(Ts, Ws, acc, wv, lq, quad);

    #pragma unroll
    for (int rt = 0; rt < 2; rt++)
        #pragma unroll
        for (int ct = 0; ct < 8; ct++)
            #pragma unroll
            for (int rg = 0; rg < 4; rg++){
                int r = node0 + wv*32 + rt*16 + quad*4 + rg;
                int c = ct*16 + lq;
                Ah[(size_t)r*HID + c] = (_Float16)(acc[rt][ct][rg] + b1s[c]);
            }
}

// -------- edge kernel: h = relu(A[src]-B[dst]) @ W2 + b2 ; segmented max into agg --------
// Register gather into MFMA; epilogue: C -> LDS (reusing Ws), per-64-row run compression.
// Interior runs (sole writer) -> plain store; boundary runs -> atomicMax. ~0.5K atomics/block.
__launch_bounds__(256, 4)
__global__ void k_edge(const uint2* __restrict__ sedge,
                       const _Float16* __restrict__ Ah, const _Float16* __restrict__ Bh,
                       const _Float16* __restrict__ w2T, const float* __restrict__ lb2,
                       uint32_t* __restrict__ agg){
    __shared__ _Float16 Ws[128*LP];
    __shared__ int ss_s[128];
    __shared__ int ds_s[128];
    __shared__ float b2s[128];
    const int tid = threadIdx.x;
    // XCD swizzle: consecutive logical tiles (sharing B[dst] rows) on the same XCD
    const int bid = blockIdx.x;
    const int lb  = (bid & 7) * (E2/128/8) + (bid >> 3);
    const int e0 = lb * 128;
    const int row = tid >> 1, half = tid & 1;

    if (tid < 128){
        uint2 e = sedge[e0 + tid];
        ss_s[tid] = (int)e.x; ds_s[tid] = (int)e.y;
        b2s[tid] = lb2[tid];
    }
    stage_copy(w2T + row*HID + half*64, Ws + row*LP + half*64);
    __syncthreads();

    const int wv = tid >> 6, lane = tid & 63, lq = lane & 15, quad = lane >> 4;
    const int r0 = wv*32 + lq, r1 = wv*32 + 16 + lq;
    const _Float16* a0p = Ah + (size_t)ss_s[r0]*HID + quad*8;
    const _Float16* a1p = Ah + (size_t)ss_s[r1]*HID + quad*8;
    const _Float16* b0p = Bh + (size_t)ds_s[r0]*HID + quad*8;
    const _Float16* b1p = Bh + (size_t)ds_s[r1]*HID + quad*8;

    f32x4 acc[2][8];
    #pragma unroll
    for (int a = 0; a < 2; a++)
        #pragma unroll
        for (int b = 0; b < 8; b++)
            acc[a][b] = (f32x4){0.f, 0.f, 0.f, 0.f};

    const h8v zero8 = (h8v)(_Float16)0;
    #pragma unroll
    for (int k0 = 0; k0 < 128; k0 += 32){
        h8v a0 = *(const h8v*)(a0p + k0) - *(const h8v*)(b0p + k0);
        h8v a1 = *(const h8v*)(a1p + k0) - *(const h8v*)(b1p + k0);
        a0 = __builtin_elementwise_max(a0, zero8);
        a1 = __builtin_elementwise_max(a1, zero8);
        #pragma unroll
        for (int ct = 0; ct < 8; ct++){
            h8v b = *(const h8v*)(Ws + (ct*16 + lq)*LP + k0 + quad*8);
            acc[0][ct] = __builtin_amdgcn_mfma_f32_16x16x32_f16(a0, b, acc[0][ct], 0, 0, 0);
            acc[1][ct] = __builtin_amdgcn_mfma_f32_16x16x32_f16(a1, b, acc[1][ct], 0, 0, 0);
        }
    }

    __syncthreads();                 // all Ws reads complete -> reuse as C buffer
    _Float16* Cs = Ws;
    #pragma unroll
    for (int rt = 0; rt < 2; rt++)
        #pragma unroll
        for (int ct = 0; ct < 8; ct++)
            #pragma unroll
            for (int rg = 0; rg < 4; rg++){
                int rr = wv*32 + rt*16 + quad*4 + rg;
                int c  = ct*16 + lq;
                Cs[rr*LP + c] = (_Float16)(acc[rt][ct][rg] + b2s[c]);
            }
    __syncthreads();

    // per-64-row segmented run-max; dst-sorted => each dst is one contiguous global run.
    // Runs strictly interior to this window have it as SOLE writer -> plain store.
    // Runs touching window edges may continue elsewhere -> atomicMax. Wave-uniform branches.
    {
        const int c = tid & 127, hf = tid >> 7;
        const int base = hf * 64;
        int pd = ds_s[base];
        float cur = (float)Cs[base*LP + c];
        bool bnd = true;                       // current run touches window start
        for (int r = base + 1; r < base + 64; r++){
            int d = ds_s[r];
            float v = (float)Cs[r*LP + c];
            if (d != pd){
                uint32_t ev = encf(cur);
                if (bnd) atomicMax(&agg[(size_t)pd*HID + c], ev);
                else     agg[(size_t)pd*HID + c] = ev;
                bnd = false;
                pd = d; cur = v;
            } else {
                cur = fmaxf(cur, v);
            }
        }
        atomicMax(&agg[(size_t)pd*HID + c], encf(cur));  // last run touches window end
    }
}

// -------- global nn: out = relu(agg@G1 + c1) @ G2 + c2 --------
__launch_bounds__(256, 2)
__global__ void k_gnn(const uint32_t* __restrict__ agg,
                      const _Float16* __restrict__ g1T, const _Float16* __restrict__ g2T,
                      const float* __restrict__ gb1, const float* __restrict__ gb2,
                      float* __restrict__ outf, _Float16* __restrict__ outh){
    __shared__ _Float16 Ts[128*LP];
    __shared__ _Float16 Ws[128*LP];
    __shared__ float c1s[128];
    __shared__ float c2s[128];
    const int tid = threadIdx.x;
    const int node0 = blockIdx.x * 128;
    if (tid < 128){ c1s[tid] = gb1[tid]; c2s[tid] = gb2[tid]; }
    const int row = tid >> 1, half = tid & 1;
    _Float16* lW = Ws + row*LP + half*64;

    {   // decode agg tile + stage G1^T
        const uint4* ga = (const uint4*)(agg + (size_t)(node0 + row)*HID + half*64);
        _Float16* lt = Ts + row*LP + half*64;
        #pragma unroll
        for (int j = 0; j < 16; j++){
            uint4 u = ga[j];
            uint2 o; o.x = pkh(decf(u.x), decf(u.y)); o.y = pkh(decf(u.z), decf(u.w));
            *(uint2*)(lt + j*4) = o;
        }
        stage_copy(g1T + row*HID + half*64, lW);
    }
    __syncthreads();

    const int wv = tid >> 6, lane = tid & 63, lq = lane & 15, quad = lane >> 4;
    f32x4 acc[2][8];
    #pragma unroll
    for (int a = 0; a < 2; a++)
        #pragma unroll
        for (int b = 0; b < 8; b++)
            acc[a][b] = (f32x4){0.f, 0.f, 0.f, 0.f};

    gemm_tile(Ts, Ws, acc, wv, lq, quad);
    __syncthreads();

    // P = relu(acc + c1) -> Ts ; restage Ws <- G2^T
    #pragma unroll
    for (int rt = 0; rt < 2; rt++)
        #pragma unroll
        for (int ct = 0; ct < 8; ct++)
            #pragma unroll
            for (int rg = 0; rg < 4; rg++){
                int rr = wv*32 + rt*16 + quad*4 + rg;
                int c  = ct*16 + lq;
                Ts[rr*LP + c] = (_Float16)fmaxf(acc[rt][ct][rg] + c1s[c], 0.f);
            }
    stage_copy(g2T + row*HID + half*64, lW);
    __syncthreads();

    #pragma unroll
    for (int a = 0; a < 2; a++)
        #pragma unroll
        for (int b = 0; b < 8; b++)
            acc[a][b] = (f32x4){0.f, 0.f, 0.f, 0.f};

    gemm_tile(Ts, Ws, acc, wv, lq, quad);

    #pragma unroll
    for (int rt = 0; rt < 2; rt++)
        #pragma unroll
        for (int ct = 0; ct < 8; ct++)
            #pragma unroll
            for (int rg = 0; rg < 4; rg++){
                int r = node0 + wv*32 + rt*16 + quad*4 + rg;
                int c = ct*16 + lq;
                float v = acc[rt][ct][rg] + c2s[c];
                if (outf) outf[(size_t)r*HID + c] = v;
                else      outh[(size_t)r*HID + c] = (_Float16)v;
            }
}

extern "C" void kernel_launch(void* const* d_in, const int* in_sizes, int n_in,
                              void* d_out, int out_size, void* d_ws, size_t ws_size,
                              hipStream_t stream){
    const float* x   = (const float*)d_in[0];
    const float* pos = (const float*)d_in[1];
    const int*   ei  = (const int*)d_in[2];
    const float* W[16];
    for (int i = 0; i < 16; i++) W[i] = (const float*)d_in[3 + i];
    // per layer l: lw1=W[8l+0] lb1=+1 lw2=+2 lb2=+3 gw1=+4 gb1=+5 gw2=+6 gb2=+7

    uint8_t* p = (uint8_t*)d_ws;
    _Float16* wT[10];
    for (int i = 0; i < 10; i++) wT[i] = (_Float16*)(p + (size_t)i * 32768);
    size_t off = 10 * 32768;
    _Float16* h0 = (_Float16*)(p + off); off += (size_t)NN * HID * 2;
    _Float16* Ah = (_Float16*)(p + off); off += (size_t)NN * HID * 2;
    _Float16* Bh = (_Float16*)(p + off); off += (size_t)NN * HID * 2;
    uint32_t* agg = (uint32_t*)(p + off); off += (size_t)NN * HID * 4;
    uint32_t* cnt = (uint32_t*)(p + off); off += (size_t)NN * 4;
    uint32_t* cur = (uint32_t*)(p + off); off += (size_t)NN * 4;
    uint32_t* bsum = (uint32_t*)(p + off); off += 256 * 4;
    uint32_t* bofs = (uint32_t*)(p + off); off += 256 * 4;
    uint2* sedge = (uint2*)(p + off); off += (size_t)E2 * 8;
    (void)ws_size; (void)in_sizes; (void)n_in; (void)out_size;

    // weight transpose+cvt: slots per layer: W1a^T, W1b^T, W2^T, G1^T, G2^T
    WT wt;
    for (int l = 0; l < 2; l++){
        wt.s[5*l + 0] = W[8*l + 0];
        wt.s[5*l + 1] = W[8*l + 0] + 128*128;
        wt.s[5*l + 2] = W[8*l + 2];
        wt.s[5*l + 3] = W[8*l + 4];
        wt.s[5*l + 4] = W[8*l + 6];
        for (int j = 0; j < 5; j++) wt.d[5*l + j] = wT[5*l + j];
    }
    k_wT_all<<<640, 256, 0, stream>>>(wt);

    // dst-sorted edge list (shared by both layers)
    k_init_cnt<<<NN/256, 256, 0, stream>>>(cnt);
    k_hist<<<NE/256, 256, 0, stream>>>(ei, cnt);
    k_scan1<<<256, 256, 0, stream>>>(cnt, bsum);
    k_scan2<<<1, 256, 0, stream>>>(bsum, bofs);
    k_scan3<<<256, 256, 0, stream>>>(cnt, bofs, cur);
    k_scatter<<<(E2 + 255)/256, 256, 0, stream>>>(ei, cur, sedge);

    for (int l = 0; l < 2; l++){
        const float* lb1 = W[8*l + 1], *lb2 = W[8*l + 3];
        const float* gb1 = W[8*l + 5], *gb2 = W[8*l + 7];
        k_ab<<<NN/128, 256, 0, stream>>>(l == 0 ? x : nullptr, l == 0 ? nullptr : h0,
                                         pos, wT[5*l + 0], wT[5*l + 1], lb1, Ah, Bh);
        k_init_agg<<<(NN*HID/4)/256, 256, 0, stream>>>(agg);
        k_edge<<<E2/128, 256, 0, stream>>>(sedge, Ah, Bh, wT[5*l + 2], lb2, agg);
        k_gnn<<<NN/128, 256, 0, stream>>>(agg, wT[5*l + 3], wT[5*l + 4], gb1, gb2,
                                          l == 0 ? nullptr : (float*)d_out,
                                          l == 0 ? h0 : nullptr);
    }
}

// Round 5
// 537.044 us; speedup vs baseline: 1.7482x; 1.1346x over previous
//
#include <hip/hip_runtime.h>
#include <hip/hip_bf16.h>
#include <stdint.h>

#define NN 65536
#define NE 1048576
#define E2 (NE + NN)      // edges + self loops = 1,114,112 = 8704*128
#define HID 128
#define LP 136            // LDS row pitch in fp16 elements (272 B)
#define RMAX 64           // max runs held in the LDS run-table (overflow -> global atomics)
#define TP 129            // run-table stride in words (bank-rotates rows)
#define ENC_NEG 0x007FFFFFu   // encf(-inf)

typedef _Float16 h8v __attribute__((ext_vector_type(8)));
typedef __fp16 fp16x2 __attribute__((ext_vector_type(2)));
typedef __attribute__((ext_vector_type(4))) float f32x4;

// pack two fp32 -> packed fp16 (RTZ, v_cvt_pkrtz_f16_f32)
__device__ __forceinline__ uint32_t pkh(float a, float b){
    union { fp16x2 h; uint32_t u; } v;
    v.h = __builtin_amdgcn_cvt_pkrtz(a, b);
    return v.u;
}
// monotone float->uint encoding for unsigned atomicMax
__device__ __forceinline__ uint32_t encf(float x){
    union { float f; uint32_t u; } v; v.f = x;
    return (v.u & 0x80000000u) ? ~v.u : (v.u | 0x80000000u);
}
__device__ __forceinline__ float decf(uint32_t u){
    union { uint32_t u; float f; } v;
    v.u = (u & 0x80000000u) ? (u ^ 0x80000000u) : ~u;
    return v.f;
}

// ---- stage one 64-elem half-row into LDS ----
__device__ __forceinline__ void stage_copy(const _Float16* g, _Float16* l){
    const uint4* gs = (const uint4*)g; uint4* ls = (uint4*)l;
    #pragma unroll
    for (int j = 0; j < 8; j++) ls[j] = gs[j];
}
__device__ __forceinline__ void stage_cvt(const float* g, _Float16* l){
    const float4* gs = (const float4*)g; uint4* ls = (uint4*)l;
    #pragma unroll
    for (int j = 0; j < 8; j++){
        float4 f0 = gs[2*j], f1 = gs[2*j+1];
        uint4 o; o.x = pkh(f0.x, f0.y); o.y = pkh(f0.z, f0.w);
        o.z = pkh(f1.x, f1.y); o.w = pkh(f1.z, f1.w);
        ls[j] = o;
    }
}

// 128x128x128 fp16 GEMM tile from LDS (used by k_ab / k_gnn)
__device__ __forceinline__ void gemm_tile(const _Float16* Ts, const _Float16* Ws,
                                          f32x4 (&acc)[2][8], int wv, int lq, int quad){
    #pragma unroll
    for (int k0 = 0; k0 < 128; k0 += 32){
        h8v af[2], bfr[8];
        #pragma unroll
        for (int rt = 0; rt < 2; rt++)
            af[rt] = *(const h8v*)(Ts + (wv*32 + rt*16 + lq)*LP + k0 + quad*8);
        #pragma unroll
        for (int ct = 0; ct < 8; ct++)
            bfr[ct] = *(const h8v*)(Ws + (ct*16 + lq)*LP + k0 + quad*8);
        #pragma unroll
        for (int rt = 0; rt < 2; rt++)
            #pragma unroll
            for (int ct = 0; ct < 8; ct++)
                acc[rt][ct] = __builtin_amdgcn_mfma_f32_16x16x32_f16(
                                  af[rt], bfr[ct], acc[rt][ct], 0, 0, 0);
    }
}

// ---------------- prep kernels ----------------
struct WT { const float* s[10]; _Float16* d[10]; };
__global__ void k_wT_all(WT w){
    int m = blockIdx.x >> 6;                       // 10 matrices x 64 blocks
    int t = (blockIdx.x & 63) * 256 + threadIdx.x; // 16384 elems each
    int n = t >> 7, k = t & 127;
    w.d[m][n*128 + k] = (_Float16)w.s[m][k*128 + n];
}
__global__ void k_init_cnt(uint32_t* cnt){
    int i = blockIdx.x * 256 + threadIdx.x;
    cnt[i] = 1u;                                   // self-loop pre-counted
}
__global__ void k_hist(const int* __restrict__ ei, uint32_t* cnt){
    int e = blockIdx.x * 256 + threadIdx.x;
    if (e < NE) atomicAdd(&cnt[ei[NE + e]], 1u);
}
__global__ void k_scan1(const uint32_t* __restrict__ cnt, uint32_t* __restrict__ bsum){
    __shared__ uint32_t ps[256];
    int t = threadIdx.x;
    ps[t] = cnt[blockIdx.x*256 + t]; __syncthreads();
    for (int off = 128; off > 0; off >>= 1){
        if (t < off) ps[t] += ps[t + off];
        __syncthreads();
    }
    if (t == 0) bsum[blockIdx.x] = ps[0];
}
__global__ void k_scan2(const uint32_t* __restrict__ bsum, uint32_t* __restrict__ bofs){
    __shared__ uint32_t ps[256];
    int t = threadIdx.x;
    uint32_t v = bsum[t];
    ps[t] = v; __syncthreads();
    for (int off = 1; off < 256; off <<= 1){
        uint32_t u = (t >= off) ? ps[t - off] : 0u;
        __syncthreads();
        ps[t] += u;
        __syncthreads();
    }
    bofs[t] = ps[t] - v;                           // exclusive
}
__global__ void k_scan3(const uint32_t* __restrict__ cnt, const uint32_t* __restrict__ bofs,
                        uint32_t* __restrict__ cur){
    __shared__ uint32_t ps[256];
    int t = threadIdx.x, i = blockIdx.x*256 + t;
    uint32_t v = cnt[i];
    ps[t] = v; __syncthreads();
    for (int off = 1; off < 256; off <<= 1){
        uint32_t u = (t >= off) ? ps[t - off] : 0u;
        __syncthreads();
        ps[t] += u;
        __syncthreads();
    }
    cur[i] = bofs[blockIdx.x] + ps[t] - v;         // exclusive within + block base
}
__global__ void k_scatter(const int* __restrict__ ei, uint32_t* cur,
                          uint2* __restrict__ sedge){
    int e = blockIdx.x * 256 + threadIdx.x;
    if (e >= E2) return;
    uint32_t s, d;
    if (e < NE){ s = (uint32_t)ei[e]; d = (uint32_t)ei[NE + e]; }
    else { s = d = (uint32_t)(e - NE); }
    uint32_t p = atomicAdd(&cur[d], 1u);
    sedge[p] = make_uint2(s, d);
}

// ---------------- A/B precompute: B = pos@W1b ; A = x@W1a + B + b1 ----------------
// Also initializes agg rows for its node range to enc(-inf) (replaces k_init_agg).
__launch_bounds__(256, 2)
__global__ void k_ab(const float* __restrict__ xf, const _Float16* __restrict__ xh,
                     const float* __restrict__ pos,
                     const _Float16* __restrict__ w1aT, const _Float16* __restrict__ w1bT,
                     const float* __restrict__ lb1,
                     _Float16* __restrict__ Ah, _Float16* __restrict__ Bh,
                     uint32_t* __restrict__ agg){
    __shared__ _Float16 Ts[128*LP];
    __shared__ _Float16 Ws[128*LP];
    __shared__ float b1s[128];
    const int tid = threadIdx.x;
    const int node0 = blockIdx.x * 128;
    if (tid < 128) b1s[tid] = lb1[tid];

    {   // init agg for this node range (dead workspace -> enc(-inf))
        uint4* ap = (uint4*)(agg + (size_t)node0 * HID);
        uint4 v = make_uint4(ENC_NEG, ENC_NEG, ENC_NEG, ENC_NEG);
        #pragma unroll
        for (int i = 0; i < 16; i++) ap[tid + i*256] = v;
    }

    const int row = tid >> 1, half = tid & 1;
    _Float16* lT = Ts + row*LP + half*64;
    _Float16* lW = Ws + row*LP + half*64;

    // phase 1: pos tile + W1b^T
    stage_cvt(pos + (size_t)(node0 + row)*HID + half*64, lT);
    stage_copy(w1bT + row*HID + half*64, lW);
    __syncthreads();

    const int wv = tid >> 6, lane = tid & 63, lq = lane & 15, quad = lane >> 4;
    f32x4 acc[2][8];
    #pragma unroll
    for (int a = 0; a < 2; a++)
        #pragma unroll
        for (int b = 0; b < 8; b++)
            acc[a][b] = (f32x4){0.f, 0.f, 0.f, 0.f};

    gemm_tile(Ts, Ws, acc, wv, lq, quad);
    __syncthreads();

    // save B = pos @ W1b  (C layout: col=lane&15, row=quad*4+reg)
    #pragma unroll
    for (int rt = 0; rt < 2; rt++)
        #pragma unroll
        for (int ct = 0; ct < 8; ct++)
            #pragma unroll
            for (int rg = 0; rg < 4; rg++){
                int r = node0 + wv*32 + rt*16 + quad*4 + rg;
                int c = ct*16 + lq;
                Bh[(size_t)r*HID + c] = (_Float16)acc[rt][ct][rg];
            }

    // phase 2: x tile + W1a^T, continue accumulation
    if (xh) stage_copy(xh + (size_t)(node0 + row)*HID + half*64, lT);
    else    stage_cvt (xf + (size_t)(node0 + row)*HID + half*64, lT);
    stage_copy(w1aT + row*HID + half*64, lW);
    __syncthreads();

    gemm_tile(Ts, Ws, acc, wv, lq, quad);

    #pragma unroll
    for (int rt = 0; rt < 2; rt++)
        #pragma unroll
        for (int ct = 0; ct < 8; ct++)
            #pragma unroll
            for (int rg = 0; rg < 4; rg++){
                int r = node0 + wv*32 + rt*16 + quad*4 + rg;
                int c = ct*16 + lq;
                Ah[(size_t)r*HID + c] = (_Float16)(acc[rt][ct][rg] + b1s[c]);
            }
}

// -------- edge kernel: h = relu(A[src]-B[dst]) @ W2 + b2 ; segmented max into agg --------
// Register gather -> MFMA. Epilogue: in-register 4-row segmented max -> LDS run-table
// (aliased onto Ws, ~8.5 runs/block avg) via LDS atomicMax -> single cooperative flush
// (interior runs: sole-writer plain store; first/last runs: global atomicMax).
__launch_bounds__(256, 4)
__global__ void k_edge(const uint2* __restrict__ sedge,
                       const _Float16* __restrict__ Ah, const _Float16* __restrict__ Bh,
                       const _Float16* __restrict__ w2T, const float* __restrict__ lb2,
                       uint32_t* __restrict__ agg){
    __shared__ _Float16 Ws[128*LP];                 // 34816 B; reused as run-table
    __shared__ int ss_s[128];
    __shared__ int ds_s[128];
    __shared__ float b2s[128];
    __shared__ unsigned long long masks_s[2];
    __shared__ int run_dst_s[RMAX];
    const int tid = threadIdx.x;
    // XCD swizzle: consecutive logical tiles (sharing B[dst] rows) on the same XCD
    const int bid = blockIdx.x;
    const int lb  = (bid & 7) * (E2/128/8) + (bid >> 3);
    const int e0 = lb * 128;
    const int row = tid >> 1, half = tid & 1;

    if (tid < 128){
        uint2 e = sedge[e0 + tid];
        ss_s[tid] = (int)e.x; ds_s[tid] = (int)e.y;
        b2s[tid] = lb2[tid];
    }
    stage_copy(w2T + row*HID + half*64, Ws + row*LP + half*64);
    __syncthreads();                                // sync1: ds_s/Ws visible

    // run-start ballots over rows 0..127 (waves 0 and 1)
    if (tid < 128){
        bool flag = (tid == 0) || (ds_s[tid] != ds_s[tid-1]);
        unsigned long long m = __ballot(flag);
        if ((tid & 63) == 0) masks_s[tid >> 6] = m;
    }

    const int wv = tid >> 6, lane = tid & 63, lq = lane & 15, quad = lane >> 4;
    const int r0 = wv*32 + lq, r1 = wv*32 + 16 + lq;
    const _Float16* a0p = Ah + (size_t)ss_s[r0]*HID + quad*8;
    const _Float16* a1p = Ah + (size_t)ss_s[r1]*HID + quad*8;
    const _Float16* b0p = Bh + (size_t)ds_s[r0]*HID + quad*8;
    const _Float16* b1p = Bh + (size_t)ds_s[r1]*HID + quad*8;

    f32x4 acc[2][8];
    #pragma unroll
    for (int a = 0; a < 2; a++)
        #pragma unroll
        for (int b = 0; b < 8; b++)
            acc[a][b] = (f32x4){0.f, 0.f, 0.f, 0.f};

    const h8v zero8 = (h8v)(_Float16)0;
    #pragma unroll
    for (int k0 = 0; k0 < 128; k0 += 32){
        h8v a0 = *(const h8v*)(a0p + k0) - *(const h8v*)(b0p + k0);
        h8v a1 = *(const h8v*)(a1p + k0) - *(const h8v*)(b1p + k0);
        a0 = __builtin_elementwise_max(a0, zero8);
        a1 = __builtin_elementwise_max(a1, zero8);
        #pragma unroll
        for (int ct = 0; ct < 8; ct++){
            h8v b = *(const h8v*)(Ws + (ct*16 + lq)*LP + k0 + quad*8);
            acc[0][ct] = __builtin_amdgcn_mfma_f32_16x16x32_f16(a0, b, acc[0][ct], 0, 0, 0);
            acc[1][ct] = __builtin_amdgcn_mfma_f32_16x16x32_f16(a1, b, acc[1][ct], 0, 0, 0);
        }
    }

    __syncthreads();                                // sync2: Ws reads done; masks visible
    const unsigned long long m0 = masks_s[0], m1 = masks_s[1];
    const int c0 = __popcll(m0);
    const int nruns = c0 + __popcll(m1);
    const int ntab = nruns < RMAX ? nruns : RMAX;
    uint32_t* tab = (uint32_t*)Ws;                  // RMAX*TP = 8256 words <= 8704 avail

    for (int i = tid; i < ntab*TP; i += 256) tab[i] = ENC_NEG;
    if (tid < 128){
        bool flag = (tid == 0) || (ds_s[tid] != ds_s[tid-1]);
        if (flag){
            int r;
            if (tid < 64) r = __popcll(m0 & ((2ull << tid) - 1)) - 1;
            else          r = c0 + __popcll(m1 & ((2ull << (tid-64)) - 1)) - 1;
            if (r < RMAX) run_dst_s[r] = ds_s[tid];
        }
    }
    __syncthreads();                                // sync3: tab initialized

    // in-register 4-row segmented max -> run-table
    #pragma unroll
    for (int rt = 0; rt < 2; rt++){
        const int rb = wv*32 + rt*16 + quad*4;
        int rid[4];
        #pragma unroll
        for (int i = 0; i < 4; i++){
            int r = rb + i;
            if (r < 64) rid[i] = __popcll(m0 & ((2ull << r) - 1)) - 1;
            else        rid[i] = c0 + __popcll(m1 & ((2ull << (r-64)) - 1)) - 1;
        }
        const bool b01 = rid[1] != rid[0];
        const bool b12 = rid[2] != rid[1];
        const bool b23 = rid[3] != rid[2];
        #pragma unroll
        for (int ct = 0; ct < 8; ct++){
            const int c = ct*16 + lq;
            const float bias = b2s[c];
            float v0 = acc[rt][ct][0] + bias, v1 = acc[rt][ct][1] + bias;
            float v2 = acc[rt][ct][2] + bias, v3 = acc[rt][ct][3] + bias;
            #define FLUSH(ID, R, V) do{ uint32_t ev = encf(V); \
                if (__builtin_expect((ID) < RMAX, 1)) atomicMax(&tab[(ID)*TP + c], ev); \
                else atomicMax(&agg[(size_t)ds_s[R]*HID + c], ev); }while(0)
            if (b01) FLUSH(rid[0], rb+0, v0); else v1 = fmaxf(v1, v0);
            if (b12) FLUSH(rid[1], rb+1, v1); else v2 = fmaxf(v2, v1);
            if (b23) FLUSH(rid[2], rb+2, v2); else v3 = fmaxf(v3, v2);
            FLUSH(rid[3], rb+3, v3);
            #undef FLUSH
        }
    }
    __syncthreads();                                // sync4: table complete

    // flush run-table: first/last runs shared with neighbor blocks -> atomicMax;
    // interior runs are sole-writer (dst-sorted contiguity) -> plain store.
    {
        const int c = tid & 127;
        for (int r = tid >> 7; r < ntab; r += 2){
            uint32_t v = tab[r*TP + c];
            uint32_t* dst = &agg[(size_t)run_dst_s[r]*HID + c];
            if (r == 0 || r == nruns-1 || nruns > RMAX) atomicMax(dst, v);
            else *dst = v;
        }
    }
}

// -------- global nn: out = relu(agg@G1 + c1) @ G2 + c2 --------
__launch_bounds__(256, 2)
__global__ void k_gnn(const uint32_t* __restrict__ agg,
                      const _Float16* __restrict__ g1T, const _Float16* __restrict__ g2T,
                      const float* __restrict__ gb1, const float* __restrict__ gb2,
                      float* __restrict__ outf, _Float16* __restrict__ outh){
    __shared__ _Float16 Ts[128*LP];
    __shared__ _Float16 Ws[128*LP];
    __shared__ float c1s[128];
    __shared__ float c2s[128];
    const int tid = threadIdx.x;
    const int node0 = blockIdx.x * 128;
    if (tid < 128){ c1s[tid] = gb1[tid]; c2s[tid] = gb2[tid]; }
    const int row = tid >> 1, half = tid & 1;
    _Float16* lW = Ws + row*LP + half*64;

    {   // decode agg tile + stage G1^T
        const uint4* ga = (const uint4*)(agg + (size_t)(node0 + row)*HID + half*64);
        _Float16* lt = Ts + row*LP + half*64;
        #pragma unroll
        for (int j = 0; j < 16; j++){
            uint4 u = ga[j];
            uint2 o; o.x = pkh(decf(u.x), decf(u.y)); o.y = pkh(decf(u.z), decf(u.w));
            *(uint2*)(lt + j*4) = o;
        }
        stage_copy(g1T + row*HID + half*64, lW);
    }
    __syncthreads();

    const int wv = tid >> 6, lane = tid & 63, lq = lane & 15, quad = lane >> 4;
    f32x4 acc[2][8];
    #pragma unroll
    for (int a = 0; a < 2; a++)
        #pragma unroll
        for (int b = 0; b < 8; b++)
            acc[a][b] = (f32x4){0.f, 0.f, 0.f, 0.f};

    gemm_tile(Ts, Ws, acc, wv, lq, quad);
    __syncthreads();

    // P = relu(acc + c1) -> Ts ; restage Ws <- G2^T
    #pragma unroll
    for (int rt = 0; rt < 2; rt++)
        #pragma unroll
        for (int ct = 0; ct < 8; ct++)
            #pragma unroll
            for (int rg = 0; rg < 4; rg++){
                int rr = wv*32 + rt*16 + quad*4 + rg;
                int c  = ct*16 + lq;
                Ts[rr*LP + c] = (_Float16)fmaxf(acc[rt][ct][rg] + c1s[c], 0.f);
            }
    stage_copy(g2T + row*HID + half*64, lW);
    __syncthreads();

    #pragma unroll
    for (int a = 0; a < 2; a++)
        #pragma unroll
        for (int b = 0; b < 8; b++)
            acc[a][b] = (f32x4){0.f, 0.f, 0.f, 0.f};

    gemm_tile(Ts, Ws, acc, wv, lq, quad);

    #pragma unroll
    for (int rt = 0; rt < 2; rt++)
        #pragma unroll
        for (int ct = 0; ct < 8; ct++)
            #pragma unroll
            for (int rg = 0; rg < 4; rg++){
                int r = node0 + wv*32 + rt*16 + quad*4 + rg;
                int c = ct*16 + lq;
                float v = acc[rt][ct][rg] + c2s[c];
                if (outf) outf[(size_t)r*HID + c] = v;
                else      outh[(size_t)r*HID + c] = (_Float16)v;
            }
}

extern "C" void kernel_launch(void* const* d_in, const int* in_sizes, int n_in,
                              void* d_out, int out_size, void* d_ws, size_t ws_size,
                              hipStream_t stream){
    const float* x   = (const float*)d_in[0];
    const float* pos = (const float*)d_in[1];
    const int*   ei  = (const int*)d_in[2];
    const float* W[16];
    for (int i = 0; i < 16; i++) W[i] = (const float*)d_in[3 + i];
    // per layer l: lw1=W[8l+0] lb1=+1 lw2=+2 lb2=+3 gw1=+4 gb1=+5 gw2=+6 gb2=+7

    uint8_t* p = (uint8_t*)d_ws;
    _Float16* wT[10];
    for (int i = 0; i < 10; i++) wT[i] = (_Float16*)(p + (size_t)i * 32768);
    size_t off = 10 * 32768;
    _Float16* h0 = (_Float16*)(p + off); off += (size_t)NN * HID * 2;
    _Float16* Ah = (_Float16*)(p + off); off += (size_t)NN * HID * 2;
    _Float16* Bh = (_Float16*)(p + off); off += (size_t)NN * HID * 2;
    uint32_t* agg = (uint32_t*)(p + off); off += (size_t)NN * HID * 4;
    uint32_t* cnt = (uint32_t*)(p + off); off += (size_t)NN * 4;
    uint32_t* cur = (uint32_t*)(p + off); off += (size_t)NN * 4;
    uint32_t* bsum = (uint32_t*)(p + off); off += 256 * 4;
    uint32_t* bofs = (uint32_t*)(p + off); off += 256 * 4;
    uint2* sedge = (uint2*)(p + off); off += (size_t)E2 * 8;
    (void)ws_size; (void)in_sizes; (void)n_in; (void)out_size;

    // weight transpose+cvt: slots per layer: W1a^T, W1b^T, W2^T, G1^T, G2^T
    WT wt;
    for (int l = 0; l < 2; l++){
        wt.s[5*l + 0] = W[8*l + 0];
        wt.s[5*l + 1] = W[8*l + 0] + 128*128;
        wt.s[5*l + 2] = W[8*l + 2];
        wt.s[5*l + 3] = W[8*l + 4];
        wt.s[5*l + 4] = W[8*l + 6];
        for (int j = 0; j < 5; j++) wt.d[5*l + j] = wT[5*l + j];
    }
    k_wT_all<<<640, 256, 0, stream>>>(wt);

    // dst-sorted edge list (shared by both layers)
    k_init_cnt<<<NN/256, 256, 0, stream>>>(cnt);
    k_hist<<<NE/256, 256, 0, stream>>>(ei, cnt);
    k_scan1<<<256, 256, 0, stream>>>(cnt, bsum);
    k_scan2<<<1, 256, 0, stream>>>(bsum, bofs);
    k_scan3<<<256, 256, 0, stream>>>(cnt, bofs, cur);
    k_scatter<<<(E2 + 255)/256, 256, 0, stream>>>(ei, cur, sedge);

    for (int l = 0; l < 2; l++){
        const float* lb1 = W[8*l + 1], *lb2 = W[8*l + 3];
        const float* gb1 = W[8*l + 5], *gb2 = W[8*l + 7];
        k_ab<<<NN/128, 256, 0, stream>>>(l == 0 ? x : nullptr, l == 0 ? nullptr : h0,
                                         pos, wT[5*l + 0], wT[5*l + 1], lb1, Ah, Bh, agg);
        k_edge<<<E2/128, 256, 0, stream>>>(sedge, Ah, Bh, wT[5*l + 2], lb2, agg);
        k_gnn<<<NN/128, 256, 0, stream>>>(agg, wT[5*l + 3], wT[5*l + 4], gb1, gb2,
                                          l == 0 ? nullptr : (float*)d_out,
                                          l == 0 ? h0 : nullptr);
    }
}

// Round 6
// 517.822 us; speedup vs baseline: 1.8131x; 1.0371x over previous
//
#include <hip/hip_runtime.h>
#include <hip/hip_bf16.h>
#include <stdint.h>

#define NN 65536
#define NE 1048576
#define E2 (NE + NN)      // edges + self loops = 1,114,112 = 8704*128
#define HID 128
#define LP 136            // padded LDS row pitch (fp16 elems) for k_ab3/k_gnn tiles
#define RMAX 48           // max runs in LDS run-table (overflow -> global atomics)
#define TP 129            // run-table stride in words
#define ENC_NEG 0x007FFFFFu   // encf(-inf)

typedef _Float16 h8v __attribute__((ext_vector_type(8)));
typedef __fp16 fp16x2 __attribute__((ext_vector_type(2)));
typedef __attribute__((ext_vector_type(4))) float f32x4;

__device__ __forceinline__ uint32_t pkh(float a, float b){
    union { fp16x2 h; uint32_t u; } v;
    v.h = __builtin_amdgcn_cvt_pkrtz(a, b);
    return v.u;
}
// monotone float->uint encoding for unsigned atomicMax
__device__ __forceinline__ uint32_t encf(float x){
    union { float f; uint32_t u; } v; v.f = x;
    return (v.u & 0x80000000u) ? ~v.u : (v.u | 0x80000000u);
}
__device__ __forceinline__ float decf(uint32_t u){
    union { uint32_t u; float f; } v;
    v.u = (u & 0x80000000u) ? (u ^ 0x80000000u) : ~u;
    return v.f;
}

// ---- stage one 64-elem half-row into LDS (padded LP layout) ----
__device__ __forceinline__ void stage_copy(const _Float16* g, _Float16* l){
    const uint4* gs = (const uint4*)g; uint4* ls = (uint4*)l;
    #pragma unroll
    for (int j = 0; j < 8; j++) ls[j] = gs[j];
}
__device__ __forceinline__ void stage_cvt(const float* g, _Float16* l){
    const float4* gs = (const float4*)g; uint4* ls = (uint4*)l;
    #pragma unroll
    for (int j = 0; j < 8; j++){
        float4 f0 = gs[2*j], f1 = gs[2*j+1];
        uint4 o; o.x = pkh(f0.x, f0.y); o.y = pkh(f0.z, f0.w);
        o.z = pkh(f1.x, f1.y); o.w = pkh(f1.z, f1.w);
        ls[j] = o;
    }
}

// 128x128x128 fp16 GEMM from padded LDS tiles (k_ab3 / k_gnn_ab / k_gnn)
__device__ __forceinline__ void gemm_tile(const _Float16* Ts, const _Float16* Ws,
                                          f32x4 (&acc)[2][8], int wv, int lq, int quad){
    #pragma unroll
    for (int k0 = 0; k0 < 128; k0 += 32){
        h8v af[2], bfr[8];
        #pragma unroll
        for (int rt = 0; rt < 2; rt++)
            af[rt] = *(const h8v*)(Ts + (wv*32 + rt*16 + lq)*LP + k0 + quad*8);
        #pragma unroll
        for (int ct = 0; ct < 8; ct++)
            bfr[ct] = *(const h8v*)(Ws + (ct*16 + lq)*LP + k0 + quad*8);
        #pragma unroll
        for (int rt = 0; rt < 2; rt++)
            #pragma unroll
            for (int ct = 0; ct < 8; ct++)
                acc[rt][ct] = __builtin_amdgcn_mfma_f32_16x16x32_f16(
                                  af[rt], bfr[ct], acc[rt][ct], 0, 0, 0);
    }
}

__device__ __forceinline__ void zero_acc(f32x4 (&acc)[2][8]){
    #pragma unroll
    for (int a = 0; a < 2; a++)
        #pragma unroll
        for (int b = 0; b < 8; b++)
            acc[a][b] = (f32x4){0.f, 0.f, 0.f, 0.f};
}

// ---------------- prep: weight transposes + cnt init + folded bias ----------------
struct WT { const float* s[10]; _Float16* d[10]; };
__global__ void k_prep(WT w, uint32_t* cnt,
                       const float* lb2_0, const float* gw1_0, const float* gb1_0,
                       const float* lb2_1, const float* gw1_1, const float* gb1_1,
                       float* c1p){
    int b = blockIdx.x;
    if (b < 640){
        int m = b >> 6;
        int t = (b & 63) * 256 + threadIdx.x;
        int n = t >> 7, k = t & 127;
        w.d[m][n*128 + k] = (_Float16)w.s[m][k*128 + n];
    } else if (b < 896){
        cnt[(b - 640)*256 + threadIdx.x] = 1u;        // self-loop pre-counted
    } else {
        // c1'[l][j] = gb1[j] + sum_k lb2[k]*gw1[k][j]   (folds b2 out of k_edge)
        int l = b - 896;
        int j = threadIdx.x;
        if (j < 128){
            const float* lb2 = l ? lb2_1 : lb2_0;
            const float* gw1 = l ? gw1_1 : gw1_0;
            float s = (l ? gb1_1 : gb1_0)[j];
            for (int k = 0; k < 128; k++) s += lb2[k] * gw1[k*128 + j];
            c1p[l*128 + j] = s;
        }
    }
}
__global__ void k_hist(const int* __restrict__ ei, uint32_t* cnt){
    int e = blockIdx.x * 256 + threadIdx.x;
    if (e < NE) atomicAdd(&cnt[ei[NE + e]], 1u);
}
__global__ void k_scan1(const uint32_t* __restrict__ cnt, uint32_t* __restrict__ bsum){
    __shared__ uint32_t ps[256];
    int t = threadIdx.x;
    ps[t] = cnt[blockIdx.x*256 + t]; __syncthreads();
    for (int off = 128; off > 0; off >>= 1){
        if (t < off) ps[t] += ps[t + off];
        __syncthreads();
    }
    if (t == 0) bsum[blockIdx.x] = ps[0];
}
__global__ void k_scan2(const uint32_t* __restrict__ bsum, uint32_t* __restrict__ bofs){
    __shared__ uint32_t ps[256];
    int t = threadIdx.x;
    uint32_t v = bsum[t];
    ps[t] = v; __syncthreads();
    for (int off = 1; off < 256; off <<= 1){
        uint32_t u = (t >= off) ? ps[t - off] : 0u;
        __syncthreads();
        ps[t] += u;
        __syncthreads();
    }
    bofs[t] = ps[t] - v;
}
__global__ void k_scan3(const uint32_t* __restrict__ cnt, const uint32_t* __restrict__ bofs,
                        uint32_t* __restrict__ cur){
    __shared__ uint32_t ps[256];
    int t = threadIdx.x, i = blockIdx.x*256 + t;
    uint32_t v = cnt[i];
    ps[t] = v; __syncthreads();
    for (int off = 1; off < 256; off <<= 1){
        uint32_t u = (t >= off) ? ps[t - off] : 0u;
        __syncthreads();
        ps[t] += u;
        __syncthreads();
    }
    cur[i] = bofs[blockIdx.x] + ps[t] - v;
}
__global__ void k_scatter(const int* __restrict__ ei, uint32_t* cur,
                          uint2* __restrict__ sedge){
    int e = blockIdx.x * 256 + threadIdx.x;
    if (e >= E2) return;
    uint32_t s, d;
    if (e < NE){ s = (uint32_t)ei[e]; d = (uint32_t)ei[NE + e]; }
    else { s = d = (uint32_t)(e - NE); }
    uint32_t p = atomicAdd(&cur[d], 1u);
    sedge[p] = make_uint2(s, d);
}

// ---------------- k_ab3: B0 = pos@W1b0 ; B1 = pos@W1b1 ; A0 = x@W1a0 + B0 + b1_0 ----
// pos staged once for both B GEMMs; also inits agg rows to enc(-inf).
__launch_bounds__(256, 2)
__global__ void k_ab3(const float* __restrict__ x, const float* __restrict__ pos,
                      const _Float16* __restrict__ w1aT0, const _Float16* __restrict__ w1bT0,
                      const _Float16* __restrict__ w1bT1, const float* __restrict__ lb1_0,
                      _Float16* __restrict__ Ah, _Float16* __restrict__ Bh0,
                      _Float16* __restrict__ Bh1, uint32_t* __restrict__ agg){
    __shared__ _Float16 Ts[128*LP];
    __shared__ _Float16 Ws[128*LP];
    __shared__ float b1s[128];
    const int tid = threadIdx.x;
    const int node0 = blockIdx.x * 128;
    if (tid < 128) b1s[tid] = lb1_0[tid];

    {   // init agg for this node range
        uint4* ap = (uint4*)(agg + (size_t)node0 * HID);
        uint4 v = make_uint4(ENC_NEG, ENC_NEG, ENC_NEG, ENC_NEG);
        #pragma unroll
        for (int i = 0; i < 16; i++) ap[tid + i*256] = v;
    }

    const int row = tid >> 1, half = tid & 1;
    _Float16* lT = Ts + row*LP + half*64;
    _Float16* lW = Ws + row*LP + half*64;

    stage_cvt(pos + (size_t)(node0 + row)*HID + half*64, lT);
    stage_copy(w1bT0 + row*HID + half*64, lW);
    __syncthreads();

    const int wv = tid >> 6, lane = tid & 63, lq = lane & 15, quad = lane >> 4;
    f32x4 acc0[2][8], acc1[2][8];
    zero_acc(acc0);
    gemm_tile(Ts, Ws, acc0, wv, lq, quad);     // acc0 = pos @ W1b0
    __syncthreads();

    #pragma unroll
    for (int rt = 0; rt < 2; rt++)
        #pragma unroll
        for (int ct = 0; ct < 8; ct++)
            #pragma unroll
            for (int rg = 0; rg < 4; rg++){
                int r = node0 + wv*32 + rt*16 + quad*4 + rg;
                int c = ct*16 + lq;
                Bh0[(size_t)r*HID + c] = (_Float16)acc0[rt][ct][rg];
            }
    stage_copy(w1bT1 + row*HID + half*64, lW);  // Ts (pos) kept
    __syncthreads();

    zero_acc(acc1);
    gemm_tile(Ts, Ws, acc1, wv, lq, quad);     // acc1 = pos @ W1b1
    __syncthreads();

    #pragma unroll
    for (int rt = 0; rt < 2; rt++)
        #pragma unroll
        for (int ct = 0; ct < 8; ct++)
            #pragma unroll
            for (int rg = 0; rg < 4; rg++){
                int r = node0 + wv*32 + rt*16 + quad*4 + rg;
                int c = ct*16 + lq;
                Bh1[(size_t)r*HID + c] = (_Float16)acc1[rt][ct][rg];
            }
    stage_cvt(x + (size_t)(node0 + row)*HID + half*64, lT);
    stage_copy(w1aT0 + row*HID + half*64, lW);
    __syncthreads();

    gemm_tile(Ts, Ws, acc0, wv, lq, quad);     // acc0 += x @ W1a0

    #pragma unroll
    for (int rt = 0; rt < 2; rt++)
        #pragma unroll
        for (int ct = 0; ct < 8; ct++)
            #pragma unroll
            for (int rg = 0; rg < 4; rg++){
                int r = node0 + wv*32 + rt*16 + quad*4 + rg;
                int c = ct*16 + lq;
                Ah[(size_t)r*HID + c] = (_Float16)(acc0[rt][ct][rg] + b1s[c]);
            }
}

// -------- edge kernel: agg[dst] = max over edges of relu(A[src]-B[dst]) @ W2 --------
// (b2 folded into c1' downstream.) XOR-swizzled W2 in LDS (conflict-free b128).
// Register gather -> MFMA -> in-register 4-row seg-max -> LDS run-table -> single flush.
__launch_bounds__(256, 4)
__global__ void k_edge(const uint2* __restrict__ sedge,
                       const _Float16* __restrict__ Ah, const _Float16* __restrict__ Bh,
                       const _Float16* __restrict__ w2T,
                       uint32_t* __restrict__ agg){
    __shared__ _Float16 Ws[128*128];            // 32768 B, swizzled; reused as run-table
    __shared__ int ss_s[128];
    __shared__ int ds_s[128];
    __shared__ unsigned long long masks_s[2];
    __shared__ int run_dst_s[RMAX];
    const int tid = threadIdx.x;
    const int bid = blockIdx.x;
    const int lb  = (bid & 7) * (E2/128/8) + (bid >> 3);   // XCD swizzle
    const int e0 = lb * 128;
    const int row = tid >> 1, half = tid & 1;

    if (tid < 128){
        uint2 e = sedge[e0 + tid];
        ss_s[tid] = (int)e.x; ds_s[tid] = (int)e.y;
    }
    {   // swizzled stage: 16B chunk kc of row r -> slot kc ^ (r&15)
        const uint4* gs = (const uint4*)(w2T + row*HID + half*64);
        #pragma unroll
        for (int j = 0; j < 8; j++){
            int kc = half*8 + j;
            *(uint4*)(Ws + row*128 + ((kc ^ (row & 15)) << 3)) = gs[j];
        }
    }
    __syncthreads();                            // sync1: ds_s/Ws visible

    if (tid < 128){
        bool flag = (tid == 0) || (ds_s[tid] != ds_s[tid-1]);
        unsigned long long m = __ballot(flag);
        if ((tid & 63) == 0) masks_s[tid >> 6] = m;
    }

    const int wv = tid >> 6, lane = tid & 63, lq = lane & 15, quad = lane >> 4;
    const int r0 = wv*32 + lq, r1 = wv*32 + 16 + lq;
    const _Float16* a0p = Ah + (size_t)ss_s[r0]*HID + quad*8;
    const _Float16* a1p = Ah + (size_t)ss_s[r1]*HID + quad*8;
    const _Float16* b0p = Bh + (size_t)ds_s[r0]*HID + quad*8;
    const _Float16* b1p = Bh + (size_t)ds_s[r1]*HID + quad*8;

    f32x4 acc[2][8];
    zero_acc(acc);

    const h8v zero8 = (h8v)(_Float16)0;
    #pragma unroll
    for (int k0 = 0; k0 < 128; k0 += 32){
        h8v a0 = *(const h8v*)(a0p + k0) - *(const h8v*)(b0p + k0);
        h8v a1 = *(const h8v*)(a1p + k0) - *(const h8v*)(b1p + k0);
        a0 = __builtin_elementwise_max(a0, zero8);
        a1 = __builtin_elementwise_max(a1, zero8);
        const int kcb = k0 >> 3;
        #pragma unroll
        for (int ct = 0; ct < 8; ct++){
            h8v b = *(const h8v*)(Ws + (ct*16 + lq)*128 + (((kcb + quad) ^ lq) << 3));
            acc[0][ct] = __builtin_amdgcn_mfma_f32_16x16x32_f16(a0, b, acc[0][ct], 0, 0, 0);
            acc[1][ct] = __builtin_amdgcn_mfma_f32_16x16x32_f16(a1, b, acc[1][ct], 0, 0, 0);
        }
    }

    __syncthreads();                            // sync2: Ws reads done; masks visible
    const unsigned long long m0 = masks_s[0], m1 = masks_s[1];
    const int c0 = __popcll(m0);
    const int nruns = c0 + __popcll(m1);
    const int ntab = nruns < RMAX ? nruns : RMAX;
    uint32_t* tab = (uint32_t*)Ws;              // RMAX*TP = 6192 words <= 8192 avail

    for (int i = tid; i < ntab*TP; i += 256) tab[i] = ENC_NEG;
    if (tid < 128){
        bool flag = (tid == 0) || (ds_s[tid] != ds_s[tid-1]);
        if (flag){
            int r;
            if (tid < 64) r = __popcll(m0 & ((2ull << tid) - 1)) - 1;
            else          r = c0 + __popcll(m1 & ((2ull << (tid-64)) - 1)) - 1;
            if (r < RMAX) run_dst_s[r] = ds_s[tid];
        }
    }
    __syncthreads();                            // sync3: tab initialized

    #pragma unroll
    for (int rt = 0; rt < 2; rt++){
        const int rb = wv*32 + rt*16 + quad*4;
        int rid[4];
        #pragma unroll
        for (int i = 0; i < 4; i++){
            int r = rb + i;
            if (r < 64) rid[i] = __popcll(m0 & ((2ull << r) - 1)) - 1;
            else        rid[i] = c0 + __popcll(m1 & ((2ull << (r-64)) - 1)) - 1;
        }
        const bool b01 = rid[1] != rid[0];
        const bool b12 = rid[2] != rid[1];
        const bool b23 = rid[3] != rid[2];
        #pragma unroll
        for (int ct = 0; ct < 8; ct++){
            const int c = ct*16 + lq;
            float v0 = acc[rt][ct][0], v1 = acc[rt][ct][1];
            float v2 = acc[rt][ct][2], v3 = acc[rt][ct][3];
            #define FLUSH(ID, R, V) do{ uint32_t ev = encf(V); \
                if (__builtin_expect((ID) < RMAX, 1)) atomicMax(&tab[(ID)*TP + c], ev); \
                else atomicMax(&agg[(size_t)ds_s[R]*HID + c], ev); }while(0)
            if (b01) FLUSH(rid[0], rb+0, v0); else v1 = fmaxf(v1, v0);
            if (b12) FLUSH(rid[1], rb+1, v1); else v2 = fmaxf(v2, v1);
            if (b23) FLUSH(rid[2], rb+2, v2); else v3 = fmaxf(v3, v2);
            FLUSH(rid[3], rb+3, v3);
            #undef FLUSH
        }
    }
    __syncthreads();                            // sync4: table complete

    {   // flush: boundary runs -> atomicMax; interior runs sole-writer -> plain store
        const int c = tid & 127;
        for (int r = tid >> 7; r < ntab; r += 2){
            uint32_t v = tab[r*TP + c];
            uint32_t* dst = &agg[(size_t)run_dst_s[r]*HID + c];
            if (r == 0 || r == nruns-1 || nruns > RMAX) atomicMax(dst, v);
            else *dst = v;
        }
    }
}

// -------- fused layer-0 global nn + layer-1 A: out0 = relu((agg)@G1 + c1')@G2 + c2 ;
//          A1 = out0@W1a1 + B1 + b1_1 ; re-inits agg rows for layer 1 --------
__launch_bounds__(256, 2)
__global__ void k_gnn_ab(uint32_t* __restrict__ agg,
                         const _Float16* __restrict__ g1T, const _Float16* __restrict__ g2T,
                         const float* __restrict__ c1p, const float* __restrict__ gb2,
                         const _Float16* __restrict__ w1aT1, const _Float16* __restrict__ Bh1,
                         const float* __restrict__ lb1_1,
                         _Float16* __restrict__ Ah){
    __shared__ _Float16 Ts[128*LP];
    __shared__ _Float16 Ws[128*LP];
    __shared__ float c1s[128];
    __shared__ float c2s[128];
    __shared__ float b1s[128];
    const int tid = threadIdx.x;
    const int node0 = blockIdx.x * 128;
    if (tid < 128){ c1s[tid] = c1p[tid]; c2s[tid] = gb2[tid]; b1s[tid] = lb1_1[tid]; }
    const int row = tid >> 1, half = tid & 1;
    _Float16* lW = Ws + row*LP + half*64;

    {   // decode agg tile (+re-init to enc(-inf)) and stage G1^T
        uint4* ga = (uint4*)(agg + (size_t)(node0 + row)*HID + half*64);
        _Float16* lt = Ts + row*LP + half*64;
        const uint4 vneg = make_uint4(ENC_NEG, ENC_NEG, ENC_NEG, ENC_NEG);
        #pragma unroll
        for (int j = 0; j < 16; j++){
            uint4 u = ga[j];
            ga[j] = vneg;
            uint2 o; o.x = pkh(decf(u.x), decf(u.y)); o.y = pkh(decf(u.z), decf(u.w));
            *(uint2*)(lt + j*4) = o;
        }
        stage_copy(g1T + row*HID + half*64, lW);
    }
    __syncthreads();

    const int wv = tid >> 6, lane = tid & 63, lq = lane & 15, quad = lane >> 4;
    f32x4 acc[2][8];
    zero_acc(acc);
    gemm_tile(Ts, Ws, acc, wv, lq, quad);       // agg @ G1
    __syncthreads();

    #pragma unroll
    for (int rt = 0; rt < 2; rt++)
        #pragma unroll
        for (int ct = 0; ct < 8; ct++)
            #pragma unroll
            for (int rg = 0; rg < 4; rg++){
                int rr = wv*32 + rt*16 + quad*4 + rg;
                int c  = ct*16 + lq;
                Ts[rr*LP + c] = (_Float16)fmaxf(acc[rt][ct][rg] + c1s[c], 0.f);
            }
    stage_copy(g2T + row*HID + half*64, lW);
    __syncthreads();

    zero_acc(acc);
    gemm_tile(Ts, Ws, acc, wv, lq, quad);       // P @ G2
    __syncthreads();

    #pragma unroll
    for (int rt = 0; rt < 2; rt++)              // out0 -> Ts (fp16), stage W1a1^T
        #pragma unroll
        for (int ct = 0; ct < 8; ct++)
            #pragma unroll
            for (int rg = 0; rg < 4; rg++){
                int rr = wv*32 + rt*16 + quad*4 + rg;
                int c  = ct*16 + lq;
                Ts[rr*LP + c] = (_Float16)(acc[rt][ct][rg] + c2s[c]);
            }
    stage_copy(w1aT1 + row*HID + half*64, lW);
    __syncthreads();

    zero_acc(acc);
    gemm_tile(Ts, Ws, acc, wv, lq, quad);       // out0 @ W1a1
    __syncthreads();

    stage_copy(Bh1 + (size_t)(node0 + row)*HID + half*64, Ts + row*LP + half*64);
    __syncthreads();

    #pragma unroll
    for (int rt = 0; rt < 2; rt++)
        #pragma unroll
        for (int ct = 0; ct < 8; ct++)
            #pragma unroll
            for (int rg = 0; rg < 4; rg++){
                int rr = wv*32 + rt*16 + quad*4 + rg;
                int c  = ct*16 + lq;
                float v = acc[rt][ct][rg] + (float)Ts[rr*LP + c] + b1s[c];
                Ah[(size_t)(node0 + rr)*HID + c] = (_Float16)v;
            }
}

// -------- final global nn: out = relu(agg@G1 + c1') @ G2 + c2 --------
__launch_bounds__(256, 2)
__global__ void k_gnn(const uint32_t* __restrict__ agg,
                      const _Float16* __restrict__ g1T, const _Float16* __restrict__ g2T,
                      const float* __restrict__ c1p, const float* __restrict__ gb2,
                      float* __restrict__ outf){
    __shared__ _Float16 Ts[128*LP];
    __shared__ _Float16 Ws[128*LP];
    __shared__ float c1s[128];
    __shared__ float c2s[128];
    const int tid = threadIdx.x;
    const int node0 = blockIdx.x * 128;
    if (tid < 128){ c1s[tid] = c1p[tid]; c2s[tid] = gb2[tid]; }
    const int row = tid >> 1, half = tid & 1;
    _Float16* lW = Ws + row*LP + half*64;

    {   // decode agg tile + stage G1^T
        const uint4* ga = (const uint4*)(agg + (size_t)(node0 + row)*HID + half*64);
        _Float16* lt = Ts + row*LP + half*64;
        #pragma unroll
        for (int j = 0; j < 16; j++){
            uint4 u = ga[j];
            uint2 o; o.x = pkh(decf(u.x), decf(u.y)); o.y = pkh(decf(u.z), decf(u.w));
            *(uint2*)(lt + j*4) = o;
        }
        stage_copy(g1T + row*HID + half*64, lW);
    }
    __syncthreads();

    const int wv = tid >> 6, lane = tid & 63, lq = lane & 15, quad = lane >> 4;
    f32x4 acc[2][8];
    zero_acc(acc);
    gemm_tile(Ts, Ws, acc, wv, lq, quad);
    __syncthreads();

    #pragma unroll
    for (int rt = 0; rt < 2; rt++)
        #pragma unroll
        for (int ct = 0; ct < 8; ct++)
            #pragma unroll
            for (int rg = 0; rg < 4; rg++){
                int rr = wv*32 + rt*16 + quad*4 + rg;
                int c  = ct*16 + lq;
                Ts[rr*LP + c] = (_Float16)fmaxf(acc[rt][ct][rg] + c1s[c], 0.f);
            }
    stage_copy(g2T + row*HID + half*64, lW);
    __syncthreads();

    zero_acc(acc);
    gemm_tile(Ts, Ws, acc, wv, lq, quad);

    #pragma unroll
    for (int rt = 0; rt < 2; rt++)
        #pragma unroll
        for (int ct = 0; ct < 8; ct++)
            #pragma unroll
            for (int rg = 0; rg < 4; rg++){
                int r = node0 + wv*32 + rt*16 + quad*4 + rg;
                int c = ct*16 + lq;
                outf[(size_t)r*HID + c] = acc[rt][ct][rg] + c2s[c];
            }
}

extern "C" void kernel_launch(void* const* d_in, const int* in_sizes, int n_in,
                              void* d_out, int out_size, void* d_ws, size_t ws_size,
                              hipStream_t stream){
    const float* x   = (const float*)d_in[0];
    const float* pos = (const float*)d_in[1];
    const int*   ei  = (const int*)d_in[2];
    const float* W[16];
    for (int i = 0; i < 16; i++) W[i] = (const float*)d_in[3 + i];
    // per layer l: lw1=W[8l+0] lb1=+1 lw2=+2 lb2=+3 gw1=+4 gb1=+5 gw2=+6 gb2=+7

    uint8_t* p = (uint8_t*)d_ws;
    _Float16* wT[10];
    for (int i = 0; i < 10; i++) wT[i] = (_Float16*)(p + (size_t)i * 32768);
    size_t off = 10 * 32768;
    _Float16* Ah  = (_Float16*)(p + off); off += (size_t)NN * HID * 2;
    _Float16* Bh0 = (_Float16*)(p + off); off += (size_t)NN * HID * 2;
    _Float16* Bh1 = (_Float16*)(p + off); off += (size_t)NN * HID * 2;
    uint32_t* agg = (uint32_t*)(p + off); off += (size_t)NN * HID * 4;
    uint32_t* cnt = (uint32_t*)(p + off); off += (size_t)NN * 4;
    uint32_t* cur = (uint32_t*)(p + off); off += (size_t)NN * 4;
    uint32_t* bsum = (uint32_t*)(p + off); off += 256 * 4;
    uint32_t* bofs = (uint32_t*)(p + off); off += 256 * 4;
    float* c1p = (float*)(p + off); off += 256 * 4;
    uint2* sedge = (uint2*)(p + off); off += (size_t)E2 * 8;
    (void)ws_size; (void)in_sizes; (void)n_in; (void)out_size;

    // weight transpose slots per layer: W1a^T, W1b^T, W2^T, G1^T, G2^T
    WT wt;
    for (int l = 0; l < 2; l++){
        wt.s[5*l + 0] = W[8*l + 0];
        wt.s[5*l + 1] = W[8*l + 0] + 128*128;
        wt.s[5*l + 2] = W[8*l + 2];
        wt.s[5*l + 3] = W[8*l + 4];
        wt.s[5*l + 4] = W[8*l + 6];
        for (int j = 0; j < 5; j++) wt.d[5*l + j] = wT[5*l + j];
    }
    k_prep<<<898, 256, 0, stream>>>(wt, cnt, W[3], W[4], W[5], W[11], W[12], W[13], c1p);

    // dst-sorted edge list (shared by both layers)
    k_hist<<<NE/256, 256, 0, stream>>>(ei, cnt);
    k_scan1<<<256, 256, 0, stream>>>(cnt, bsum);
    k_scan2<<<1, 256, 0, stream>>>(bsum, bofs);
    k_scan3<<<256, 256, 0, stream>>>(cnt, bofs, cur);
    k_scatter<<<(E2 + 255)/256, 256, 0, stream>>>(ei, cur, sedge);

    k_ab3<<<NN/128, 256, 0, stream>>>(x, pos, wT[0], wT[1], wT[6], W[1],
                                      Ah, Bh0, Bh1, agg);
    k_edge<<<E2/128, 256, 0, stream>>>(sedge, Ah, Bh0, wT[2], agg);
    k_gnn_ab<<<NN/128, 256, 0, stream>>>(agg, wT[3], wT[4], c1p, W[7],
                                         wT[5], Bh1, W[9], Ah);
    k_edge<<<E2/128, 256, 0, stream>>>(sedge, Ah, Bh1, wT[7], agg);
    k_gnn<<<NN/128, 256, 0, stream>>>(agg, wT[8], wT[9], c1p + 128, W[15],
                                      (float*)d_out);
}

// Round 7
// 517.503 us; speedup vs baseline: 1.8142x; 1.0006x over previous
//
#include <hip/hip_runtime.h>
#include <hip/hip_bf16.h>
#include <stdint.h>

#define NN 65536
#define NE 1048576
#define E2 (NE + NN)      // edges + self loops = 1,114,112 = 8704*128
#define HID 128
#define LP 136            // padded LDS row pitch (fp16 elems) for k_ab3/k_gnn tiles
#define RMAX 48           // max runs in LDS run-table (overflow -> global atomics)
#define TP 129            // run-table stride in words
#define ENC_NEG 0x007FFFFFu   // encf(-inf)

typedef _Float16 h8v __attribute__((ext_vector_type(8)));
typedef __fp16 fp16x2 __attribute__((ext_vector_type(2)));
typedef __attribute__((ext_vector_type(4))) float f32x4;

__device__ __forceinline__ uint32_t pkh(float a, float b){
    union { fp16x2 h; uint32_t u; } v;
    v.h = __builtin_amdgcn_cvt_pkrtz(a, b);
    return v.u;
}
// monotone float->uint encoding for unsigned atomicMax
__device__ __forceinline__ uint32_t encf(float x){
    union { float f; uint32_t u; } v; v.f = x;
    return (v.u & 0x80000000u) ? ~v.u : (v.u | 0x80000000u);
}
__device__ __forceinline__ float decf(uint32_t u){
    union { uint32_t u; float f; } v;
    v.u = (u & 0x80000000u) ? (u ^ 0x80000000u) : ~u;
    return v.f;
}

// ---- stage one 64-elem half-row into LDS (padded LP layout) ----
__device__ __forceinline__ void stage_copy(const _Float16* g, _Float16* l){
    const uint4* gs = (const uint4*)g; uint4* ls = (uint4*)l;
    #pragma unroll
    for (int j = 0; j < 8; j++) ls[j] = gs[j];
}
__device__ __forceinline__ void stage_cvt(const float* g, _Float16* l){
    const float4* gs = (const float4*)g; uint4* ls = (uint4*)l;
    #pragma unroll
    for (int j = 0; j < 8; j++){
        float4 f0 = gs[2*j], f1 = gs[2*j+1];
        uint4 o; o.x = pkh(f0.x, f0.y); o.y = pkh(f0.z, f0.w);
        o.z = pkh(f1.x, f1.y); o.w = pkh(f1.z, f1.w);
        ls[j] = o;
    }
}

// 128x128x128 fp16 GEMM from padded LDS tiles (k_ab3 / k_gnn_ab / k_gnn)
__device__ __forceinline__ void gemm_tile(const _Float16* Ts, const _Float16* Ws,
                                          f32x4 (&acc)[2][8], int wv, int lq, int quad){
    #pragma unroll
    for (int k0 = 0; k0 < 128; k0 += 32){
        h8v af[2], bfr[8];
        #pragma unroll
        for (int rt = 0; rt < 2; rt++)
            af[rt] = *(const h8v*)(Ts + (wv*32 + rt*16 + lq)*LP + k0 + quad*8);
        #pragma unroll
        for (int ct = 0; ct < 8; ct++)
            bfr[ct] = *(const h8v*)(Ws + (ct*16 + lq)*LP + k0 + quad*8);
        #pragma unroll
        for (int rt = 0; rt < 2; rt++)
            #pragma unroll
            for (int ct = 0; ct < 8; ct++)
                acc[rt][ct] = __builtin_amdgcn_mfma_f32_16x16x32_f16(
                                  af[rt], bfr[ct], acc[rt][ct], 0, 0, 0);
    }
}

__device__ __forceinline__ void zero_acc(f32x4 (&acc)[2][8]){
    #pragma unroll
    for (int a = 0; a < 2; a++)
        #pragma unroll
        for (int b = 0; b < 8; b++)
            acc[a][b] = (f32x4){0.f, 0.f, 0.f, 0.f};
}

// ---------------- prep: weight transposes + cnt init + folded bias ----------------
struct WT { const float* s[10]; _Float16* d[10]; };
__global__ void k_prep(WT w, uint32_t* cnt,
                       const float* lb2_0, const float* gw1_0, const float* gb1_0,
                       const float* lb2_1, const float* gw1_1, const float* gb1_1,
                       float* c1p){
    int b = blockIdx.x;
    if (b < 640){
        int m = b >> 6;
        int t = (b & 63) * 256 + threadIdx.x;
        int n = t >> 7, k = t & 127;
        w.d[m][n*128 + k] = (_Float16)w.s[m][k*128 + n];
    } else if (b < 896){
        cnt[(b - 640)*256 + threadIdx.x] = 1u;        // self-loop pre-counted
    } else {
        // c1'[l][j] = gb1[j] + sum_k lb2[k]*gw1[k][j]   (folds b2 out of k_edge)
        int l = b - 896;
        int j = threadIdx.x;
        if (j < 128){
            const float* lb2 = l ? lb2_1 : lb2_0;
            const float* gw1 = l ? gw1_1 : gw1_0;
            float s = (l ? gb1_1 : gb1_0)[j];
            for (int k = 0; k < 128; k++) s += lb2[k] * gw1[k*128 + j];
            c1p[l*128 + j] = s;
        }
    }
}
__global__ void k_hist(const int* __restrict__ ei, uint32_t* cnt){
    int e = blockIdx.x * 256 + threadIdx.x;
    if (e < NE) atomicAdd(&cnt[ei[NE + e]], 1u);
}
__global__ void k_scan1(const uint32_t* __restrict__ cnt, uint32_t* __restrict__ bsum){
    __shared__ uint32_t ps[256];
    int t = threadIdx.x;
    ps[t] = cnt[blockIdx.x*256 + t]; __syncthreads();
    for (int off = 128; off > 0; off >>= 1){
        if (t < off) ps[t] += ps[t + off];
        __syncthreads();
    }
    if (t == 0) bsum[blockIdx.x] = ps[0];
}
__global__ void k_scan2(const uint32_t* __restrict__ bsum, uint32_t* __restrict__ bofs){
    __shared__ uint32_t ps[256];
    int t = threadIdx.x;
    uint32_t v = bsum[t];
    ps[t] = v; __syncthreads();
    for (int off = 1; off < 256; off <<= 1){
        uint32_t u = (t >= off) ? ps[t - off] : 0u;
        __syncthreads();
        ps[t] += u;
        __syncthreads();
    }
    bofs[t] = ps[t] - v;
}
__global__ void k_scan3(const uint32_t* __restrict__ cnt, const uint32_t* __restrict__ bofs,
                        uint32_t* __restrict__ cur){
    __shared__ uint32_t ps[256];
    int t = threadIdx.x, i = blockIdx.x*256 + t;
    uint32_t v = cnt[i];
    ps[t] = v; __syncthreads();
    for (int off = 1; off < 256; off <<= 1){
        uint32_t u = (t >= off) ? ps[t - off] : 0u;
        __syncthreads();
        ps[t] += u;
        __syncthreads();
    }
    cur[i] = bofs[blockIdx.x] + ps[t] - v;
}
__global__ void k_scatter(const int* __restrict__ ei, uint32_t* cur,
                          uint2* __restrict__ sedge){
    int e = blockIdx.x * 256 + threadIdx.x;
    if (e >= E2) return;
    uint32_t s, d;
    if (e < NE){ s = (uint32_t)ei[e]; d = (uint32_t)ei[NE + e]; }
    else { s = d = (uint32_t)(e - NE); }
    uint32_t p = atomicAdd(&cur[d], 1u);
    sedge[p] = make_uint2(s, d);
}

// ---------------- k_ab3: B0 = pos@W1b0 ; B1 = pos@W1b1 ; A0 = x@W1a0 + B0 + b1_0 ----
// pos staged once for both B GEMMs; also inits agg rows to enc(-inf).
__launch_bounds__(256, 2)
__global__ void k_ab3(const float* __restrict__ x, const float* __restrict__ pos,
                      const _Float16* __restrict__ w1aT0, const _Float16* __restrict__ w1bT0,
                      const _Float16* __restrict__ w1bT1, const float* __restrict__ lb1_0,
                      _Float16* __restrict__ Ah, _Float16* __restrict__ Bh0,
                      _Float16* __restrict__ Bh1, uint32_t* __restrict__ agg){
    __shared__ _Float16 Ts[128*LP];
    __shared__ _Float16 Ws[128*LP];
    __shared__ float b1s[128];
    const int tid = threadIdx.x;
    const int node0 = blockIdx.x * 128;
    if (tid < 128) b1s[tid] = lb1_0[tid];

    {   // init agg for this node range
        uint4* ap = (uint4*)(agg + (size_t)node0 * HID);
        uint4 v = make_uint4(ENC_NEG, ENC_NEG, ENC_NEG, ENC_NEG);
        #pragma unroll
        for (int i = 0; i < 16; i++) ap[tid + i*256] = v;
    }

    const int row = tid >> 1, half = tid & 1;
    _Float16* lT = Ts + row*LP + half*64;
    _Float16* lW = Ws + row*LP + half*64;

    stage_cvt(pos + (size_t)(node0 + row)*HID + half*64, lT);
    stage_copy(w1bT0 + row*HID + half*64, lW);
    __syncthreads();

    const int wv = tid >> 6, lane = tid & 63, lq = lane & 15, quad = lane >> 4;
    f32x4 acc0[2][8], acc1[2][8];
    zero_acc(acc0);
    gemm_tile(Ts, Ws, acc0, wv, lq, quad);     // acc0 = pos @ W1b0
    __syncthreads();

    #pragma unroll
    for (int rt = 0; rt < 2; rt++)
        #pragma unroll
        for (int ct = 0; ct < 8; ct++)
            #pragma unroll
            for (int rg = 0; rg < 4; rg++){
                int r = node0 + wv*32 + rt*16 + quad*4 + rg;
                int c = ct*16 + lq;
                Bh0[(size_t)r*HID + c] = (_Float16)acc0[rt][ct][rg];
            }
    stage_copy(w1bT1 + row*HID + half*64, lW);  // Ts (pos) kept
    __syncthreads();

    zero_acc(acc1);
    gemm_tile(Ts, Ws, acc1, wv, lq, quad);     // acc1 = pos @ W1b1
    __syncthreads();

    #pragma unroll
    for (int rt = 0; rt < 2; rt++)
        #pragma unroll
        for (int ct = 0; ct < 8; ct++)
            #pragma unroll
            for (int rg = 0; rg < 4; rg++){
                int r = node0 + wv*32 + rt*16 + quad*4 + rg;
                int c = ct*16 + lq;
                Bh1[(size_t)r*HID + c] = (_Float16)acc1[rt][ct][rg];
            }
    stage_cvt(x + (size_t)(node0 + row)*HID + half*64, lT);
    stage_copy(w1aT0 + row*HID + half*64, lW);
    __syncthreads();

    gemm_tile(Ts, Ws, acc0, wv, lq, quad);     // acc0 += x @ W1a0

    #pragma unroll
    for (int rt = 0; rt < 2; rt++)
        #pragma unroll
        for (int ct = 0; ct < 8; ct++)
            #pragma unroll
            for (int rg = 0; rg < 4; rg++){
                int r = node0 + wv*32 + rt*16 + quad*4 + rg;
                int c = ct*16 + lq;
                Ah[(size_t)r*HID + c] = (_Float16)(acc0[rt][ct][rg] + b1s[c]);
            }
}

// -------- edge kernel: agg[dst] = max over edges of relu(A[src]-B[dst]) @ W2 --------
// All 16 gather loads hoisted ahead of the MFMA stream (single latency exposure).
// XOR-swizzled W2 in LDS (conflict-free b128). In-register 4-row seg-max ->
// LDS run-table -> single flush (interior runs sole-writer plain store).
__launch_bounds__(256, 3)
__global__ void k_edge(const uint2* __restrict__ sedge,
                       const _Float16* __restrict__ Ah, const _Float16* __restrict__ Bh,
                       const _Float16* __restrict__ w2T,
                       uint32_t* __restrict__ agg){
    __shared__ _Float16 Ws[128*128];            // 32768 B, swizzled; reused as run-table
    __shared__ int ss_s[128];
    __shared__ int ds_s[128];
    __shared__ unsigned long long masks_s[2];
    __shared__ int run_dst_s[RMAX];
    const int tid = threadIdx.x;
    const int bid = blockIdx.x;
    const int lb  = (bid & 7) * (E2/128/8) + (bid >> 3);   // XCD swizzle
    const int e0 = lb * 128;
    const int row = tid >> 1, half = tid & 1;

    if (tid < 128){
        uint2 e = sedge[e0 + tid];
        ss_s[tid] = (int)e.x; ds_s[tid] = (int)e.y;
    }
    {   // swizzled stage: 16B chunk kc of row r -> slot kc ^ (r&15)
        const uint4* gs = (const uint4*)(w2T + row*HID + half*64);
        #pragma unroll
        for (int j = 0; j < 8; j++){
            int kc = half*8 + j;
            *(uint4*)(Ws + row*128 + ((kc ^ (row & 15)) << 3)) = gs[j];
        }
    }
    __syncthreads();                            // sync1: ds_s/Ws visible

    if (tid < 128){
        bool flag = (tid == 0) || (ds_s[tid] != ds_s[tid-1]);
        unsigned long long m = __ballot(flag);
        if ((tid & 63) == 0) masks_s[tid >> 6] = m;
    }

    const int wv = tid >> 6, lane = tid & 63, lq = lane & 15, quad = lane >> 4;
    const int r0 = wv*32 + lq, r1 = wv*32 + 16 + lq;
    const _Float16* a0p = Ah + (size_t)ss_s[r0]*HID + quad*8;
    const _Float16* a1p = Ah + (size_t)ss_s[r1]*HID + quad*8;
    const _Float16* b0p = Bh + (size_t)ds_s[r0]*HID + quad*8;
    const _Float16* b1p = Bh + (size_t)ds_s[r1]*HID + quad*8;

    // hoist ALL 16 gather loads: one latency exposure, then a pure MFMA stream
    h8v A0[4], A1[4], B0[4], B1[4];
    #pragma unroll
    for (int i = 0; i < 4; i++){
        A0[i] = *(const h8v*)(a0p + 32*i);
        A1[i] = *(const h8v*)(a1p + 32*i);
        B0[i] = *(const h8v*)(b0p + 32*i);
        B1[i] = *(const h8v*)(b1p + 32*i);
    }

    f32x4 acc[2][8];
    zero_acc(acc);

    const h8v zero8 = (h8v)(_Float16)0;
    #pragma unroll
    for (int i = 0; i < 4; i++){
        h8v a0 = __builtin_elementwise_max(A0[i] - B0[i], zero8);
        h8v a1 = __builtin_elementwise_max(A1[i] - B1[i], zero8);
        const int kcb = i*4;
        #pragma unroll
        for (int ct = 0; ct < 8; ct++){
            h8v b = *(const h8v*)(Ws + (ct*16 + lq)*128 + (((kcb + quad) ^ lq) << 3));
            acc[0][ct] = __builtin_amdgcn_mfma_f32_16x16x32_f16(a0, b, acc[0][ct], 0, 0, 0);
            acc[1][ct] = __builtin_amdgcn_mfma_f32_16x16x32_f16(a1, b, acc[1][ct], 0, 0, 0);
        }
    }

    __syncthreads();                            // sync2: Ws reads done; masks visible
    const unsigned long long m0 = masks_s[0], m1 = masks_s[1];
    const int c0 = __popcll(m0);
    const int nruns = c0 + __popcll(m1);
    const int ntab = nruns < RMAX ? nruns : RMAX;
    uint32_t* tab = (uint32_t*)Ws;              // RMAX*TP = 6192 words <= 8192 avail

    for (int i = tid; i < ntab*TP; i += 256) tab[i] = ENC_NEG;
    if (tid < 128){
        bool flag = (tid == 0) || (ds_s[tid] != ds_s[tid-1]);
        if (flag){
            int r;
            if (tid < 64) r = __popcll(m0 & ((2ull << tid) - 1)) - 1;
            else          r = c0 + __popcll(m1 & ((2ull << (tid-64)) - 1)) - 1;
            if (r < RMAX) run_dst_s[r] = ds_s[tid];
        }
    }
    __syncthreads();                            // sync3: tab initialized

    #pragma unroll
    for (int rt = 0; rt < 2; rt++){
        const int rb = wv*32 + rt*16 + quad*4;
        int rid[4];
        #pragma unroll
        for (int i = 0; i < 4; i++){
            int r = rb + i;
            if (r < 64) rid[i] = __popcll(m0 & ((2ull << r) - 1)) - 1;
            else        rid[i] = c0 + __popcll(m1 & ((2ull << (r-64)) - 1)) - 1;
        }
        const bool b01 = rid[1] != rid[0];
        const bool b12 = rid[2] != rid[1];
        const bool b23 = rid[3] != rid[2];
        #pragma unroll
        for (int ct = 0; ct < 8; ct++){
            const int c = ct*16 + lq;
            float v0 = acc[rt][ct][0], v1 = acc[rt][ct][1];
            float v2 = acc[rt][ct][2], v3 = acc[rt][ct][3];
            #define FLUSH(ID, R, V) do{ uint32_t ev = encf(V); \
                if (__builtin_expect((ID) < RMAX, 1)) atomicMax(&tab[(ID)*TP + c], ev); \
                else atomicMax(&agg[(size_t)ds_s[R]*HID + c], ev); }while(0)
            if (b01) FLUSH(rid[0], rb+0, v0); else v1 = fmaxf(v1, v0);
            if (b12) FLUSH(rid[1], rb+1, v1); else v2 = fmaxf(v2, v1);
            if (b23) FLUSH(rid[2], rb+2, v2); else v3 = fmaxf(v3, v2);
            FLUSH(rid[3], rb+3, v3);
            #undef FLUSH
        }
    }
    __syncthreads();                            // sync4: table complete

    {   // flush: boundary runs -> atomicMax; interior runs sole-writer -> plain store
        const int c = tid & 127;
        for (int r = tid >> 7; r < ntab; r += 2){
            uint32_t v = tab[r*TP + c];
            uint32_t* dst = &agg[(size_t)run_dst_s[r]*HID + c];
            if (r == 0 || r == nruns-1 || nruns > RMAX) atomicMax(dst, v);
            else *dst = v;
        }
    }
}

// -------- fused layer-0 global nn + layer-1 A: out0 = relu((agg)@G1 + c1')@G2 + c2 ;
//          A1 = out0@W1a1 + B1 + b1_1 ; re-inits agg rows for layer 1 --------
__launch_bounds__(256, 2)
__global__ void k_gnn_ab(uint32_t* __restrict__ agg,
                         const _Float16* __restrict__ g1T, const _Float16* __restrict__ g2T,
                         const float* __restrict__ c1p, const float* __restrict__ gb2,
                         const _Float16* __restrict__ w1aT1, const _Float16* __restrict__ Bh1,
                         const float* __restrict__ lb1_1,
                         _Float16* __restrict__ Ah){
    __shared__ _Float16 Ts[128*LP];
    __shared__ _Float16 Ws[128*LP];
    __shared__ float c1s[128];
    __shared__ float c2s[128];
    __shared__ float b1s[128];
    const int tid = threadIdx.x;
    const int node0 = blockIdx.x * 128;
    if (tid < 128){ c1s[tid] = c1p[tid]; c2s[tid] = gb2[tid]; b1s[tid] = lb1_1[tid]; }
    const int row = tid >> 1, half = tid & 1;
    _Float16* lW = Ws + row*LP + half*64;

    {   // decode agg tile (+re-init to enc(-inf)) and stage G1^T
        uint4* ga = (uint4*)(agg + (size_t)(node0 + row)*HID + half*64);
        _Float16* lt = Ts + row*LP + half*64;
        const uint4 vneg = make_uint4(ENC_NEG, ENC_NEG, ENC_NEG, ENC_NEG);
        #pragma unroll
        for (int j = 0; j < 16; j++){
            uint4 u = ga[j];
            ga[j] = vneg;
            uint2 o; o.x = pkh(decf(u.x), decf(u.y)); o.y = pkh(decf(u.z), decf(u.w));
            *(uint2*)(lt + j*4) = o;
        }
        stage_copy(g1T + row*HID + half*64, lW);
    }
    __syncthreads();

    const int wv = tid >> 6, lane = tid & 63, lq = lane & 15, quad = lane >> 4;
    f32x4 acc[2][8];
    zero_acc(acc);
    gemm_tile(Ts, Ws, acc, wv, lq, quad);       // agg @ G1
    __syncthreads();

    #pragma unroll
    for (int rt = 0; rt < 2; rt++)
        #pragma unroll
        for (int ct = 0; ct < 8; ct++)
            #pragma unroll
            for (int rg = 0; rg < 4; rg++){
                int rr = wv*32 + rt*16 + quad*4 + rg;
                int c  = ct*16 + lq;
                Ts[rr*LP + c] = (_Float16)fmaxf(acc[rt][ct][rg] + c1s[c], 0.f);
            }
    stage_copy(g2T + row*HID + half*64, lW);
    __syncthreads();

    zero_acc(acc);
    gemm_tile(Ts, Ws, acc, wv, lq, quad);       // P @ G2
    __syncthreads();

    #pragma unroll
    for (int rt = 0; rt < 2; rt++)              // out0 -> Ts (fp16), stage W1a1^T
        #pragma unroll
        for (int ct = 0; ct < 8; ct++)
            #pragma unroll
            for (int rg = 0; rg < 4; rg++){
                int rr = wv*32 + rt*16 + quad*4 + rg;
                int c  = ct*16 + lq;
                Ts[rr*LP + c] = (_Float16)(acc[rt][ct][rg] + c2s[c]);
            }
    stage_copy(w1aT1 + row*HID + half*64, lW);
    __syncthreads();

    zero_acc(acc);
    gemm_tile(Ts, Ws, acc, wv, lq, quad);       // out0 @ W1a1
    __syncthreads();

    stage_copy(Bh1 + (size_t)(node0 + row)*HID + half*64, Ts + row*LP + half*64);
    __syncthreads();

    #pragma unroll
    for (int rt = 0; rt < 2; rt++)
        #pragma unroll
        for (int ct = 0; ct < 8; ct++)
            #pragma unroll
            for (int rg = 0; rg < 4; rg++){
                int rr = wv*32 + rt*16 + quad*4 + rg;
                int c  = ct*16 + lq;
                float v = acc[rt][ct][rg] + (float)Ts[rr*LP + c] + b1s[c];
                Ah[(size_t)(node0 + rr)*HID + c] = (_Float16)v;
            }
}

// -------- final global nn: out = relu(agg@G1 + c1') @ G2 + c2 --------
__launch_bounds__(256, 2)
__global__ void k_gnn(const uint32_t* __restrict__ agg,
                      const _Float16* __restrict__ g1T, const _Float16* __restrict__ g2T,
                      const float* __restrict__ c1p, const float* __restrict__ gb2,
                      float* __restrict__ outf){
    __shared__ _Float16 Ts[128*LP];
    __shared__ _Float16 Ws[128*LP];
    __shared__ float c1s[128];
    __shared__ float c2s[128];
    const int tid = threadIdx.x;
    const int node0 = blockIdx.x * 128;
    if (tid < 128){ c1s[tid] = c1p[tid]; c2s[tid] = gb2[tid]; }
    const int row = tid >> 1, half = tid & 1;
    _Float16* lW = Ws + row*LP + half*64;

    {   // decode agg tile + stage G1^T
        const uint4* ga = (const uint4*)(agg + (size_t)(node0 + row)*HID + half*64);
        _Float16* lt = Ts + row*LP + half*64;
        #pragma unroll
        for (int j = 0; j < 16; j++){
            uint4 u = ga[j];
            uint2 o; o.x = pkh(decf(u.x), decf(u.y)); o.y = pkh(decf(u.z), decf(u.w));
            *(uint2*)(lt + j*4) = o;
        }
        stage_copy(g1T + row*HID + half*64, lW);
    }
    __syncthreads();

    const int wv = tid >> 6, lane = tid & 63, lq = lane & 15, quad = lane >> 4;
    f32x4 acc[2][8];
    zero_acc(acc);
    gemm_tile(Ts, Ws, acc, wv, lq, quad);
    __syncthreads();

    #pragma unroll
    for (int rt = 0; rt < 2; rt++)
        #pragma unroll
        for (int ct = 0; ct < 8; ct++)
            #pragma unroll
            for (int rg = 0; rg < 4; rg++){
                int rr = wv*32 + rt*16 + quad*4 + rg;
                int c  = ct*16 + lq;
                Ts[rr*LP + c] = (_Float16)fmaxf(acc[rt][ct][rg] + c1s[c], 0.f);
            }
    stage_copy(g2T + row*HID + half*64, lW);
    __syncthreads();

    zero_acc(acc);
    gemm_tile(Ts, Ws, acc, wv, lq, quad);

    #pragma unroll
    for (int rt = 0; rt < 2; rt++)
        #pragma unroll
        for (int ct = 0; ct < 8; ct++)
            #pragma unroll
            for (int rg = 0; rg < 4; rg++){
                int r = node0 + wv*32 + rt*16 + quad*4 + rg;
                int c = ct*16 + lq;
                outf[(size_t)r*HID + c] = acc[rt][ct][rg] + c2s[c];
            }
}

extern "C" void kernel_launch(void* const* d_in, const int* in_sizes, int n_in,
                              void* d_out, int out_size, void* d_ws, size_t ws_size,
                              hipStream_t stream){
    const float* x   = (const float*)d_in[0];
    const float* pos = (const float*)d_in[1];
    const int*   ei  = (const int*)d_in[2];
    const float* W[16];
    for (int i = 0; i < 16; i++) W[i] = (const float*)d_in[3 + i];
    // per layer l: lw1=W[8l+0] lb1=+1 lw2=+2 lb2=+3 gw1=+4 gb1=+5 gw2=+6 gb2=+7

    uint8_t* p = (uint8_t*)d_ws;
    _Float16* wT[10];
    for (int i = 0; i < 10; i++) wT[i] = (_Float16*)(p + (size_t)i * 32768);
    size_t off = 10 * 32768;
    _Float16* Ah  = (_Float16*)(p + off); off += (size_t)NN * HID * 2;
    _Float16* Bh0 = (_Float16*)(p + off); off += (size_t)NN * HID * 2;
    _Float16* Bh1 = (_Float16*)(p + off); off += (size_t)NN * HID * 2;
    uint32_t* agg = (uint32_t*)(p + off); off += (size_t)NN * HID * 4;
    uint32_t* cnt = (uint32_t*)(p + off); off += (size_t)NN * 4;
    uint32_t* cur = (uint32_t*)(p + off); off += (size_t)NN * 4;
    uint32_t* bsum = (uint32_t*)(p + off); off += 256 * 4;
    uint32_t* bofs = (uint32_t*)(p + off); off += 256 * 4;
    float* c1p = (float*)(p + off); off += 256 * 4;
    uint2* sedge = (uint2*)(p + off); off += (size_t)E2 * 8;
    (void)ws_size; (void)in_sizes; (void)n_in; (void)out_size;

    // weight transpose slots per layer: W1a^T, W1b^T, W2^T, G1^T, G2^T
    WT wt;
    for (int l = 0; l < 2; l++){
        wt.s[5*l + 0] = W[8*l + 0];
        wt.s[5*l + 1] = W[8*l + 0] + 128*128;
        wt.s[5*l + 2] = W[8*l + 2];
        wt.s[5*l + 3] = W[8*l + 4];
        wt.s[5*l + 4] = W[8*l + 6];
        for (int j = 0; j < 5; j++) wt.d[5*l + j] = wT[5*l + j];
    }
    k_prep<<<898, 256, 0, stream>>>(wt, cnt, W[3], W[4], W[5], W[11], W[12], W[13], c1p);

    // dst-sorted edge list (shared by both layers)
    k_hist<<<NE/256, 256, 0, stream>>>(ei, cnt);
    k_scan1<<<256, 256, 0, stream>>>(cnt, bsum);
    k_scan2<<<1, 256, 0, stream>>>(bsum, bofs);
    k_scan3<<<256, 256, 0, stream>>>(cnt, bofs, cur);
    k_scatter<<<(E2 + 255)/256, 256, 0, stream>>>(ei, cur, sedge);

    k_ab3<<<NN/128, 256, 0, stream>>>(x, pos, wT[0], wT[1], wT[6], W[1],
                                      Ah, Bh0, Bh1, agg);
    k_edge<<<E2/128, 256, 0, stream>>>(sedge, Ah, Bh0, wT[2], agg);
    k_gnn_ab<<<NN/128, 256, 0, stream>>>(agg, wT[3], wT[4], c1p, W[7],
                                         wT[5], Bh1, W[9], Ah);
    k_edge<<<E2/128, 256, 0, stream>>>(sedge, Ah, Bh1, wT[7], agg);
    k_gnn<<<NN/128, 256, 0, stream>>>(agg, wT[8], wT[9], c1p + 128, W[15],
                                      (float*)d_out);
}